// Round 1
// baseline (227.588 us; speedup 1.0000x reference)
//
#include <hip/hip_runtime.h>

typedef __attribute__((ext_vector_type(4))) float f32x4;
typedef __attribute__((ext_vector_type(8))) short s16x8;

#define MFMA16(a, b, c) __builtin_amdgcn_mfma_f32_16x16x32_bf16((a), (b), (c), 0, 0, 0)

__device__ __forceinline__ unsigned short f2bf(float f) {
    union { float f; unsigned u; } v; v.f = f;
    unsigned u = v.u + 0x7FFFu + ((v.u >> 16) & 1u);
    return (unsigned short)(u >> 16);
}

__device__ __forceinline__ void gll16(const unsigned short* g, unsigned short* l) {
    __builtin_amdgcn_global_load_lds((const __attribute__((address_space(1))) void*)g,
                                     (__attribute__((address_space(3))) void*)l, 16, 0, 0);
}

// ---------------- kernel 1: convert qkv_w / proj_w fp32 -> bf16 ----------------
__global__ __launch_bounds__(256) void k_wconv(const float* __restrict__ qkv_w,
                                               const float* __restrict__ proj_w,
                                               unsigned short* __restrict__ wout) {
    int i = blockIdx.x * 256 + threadIdx.x;
    const int NQ = 3 * 512 * 512;
    float v = (i < NQ) ? qkv_w[i] : proj_w[i - NQ];
    wout[i] = f2bf(v);
}

// ---------------- kernel 2: group-norm stats (mean, rstd) per (b,g) ----------------
__global__ __launch_bounds__(256) void k_gnstats(const float* __restrict__ x,
                                                 float* __restrict__ stats) {
    int bg = blockIdx.x; // 0..511, group block is 16*1024 contiguous floats
    const float4* p = (const float4*)(x + (size_t)bg * 16384);
    float s = 0.f, ss = 0.f;
    for (int i = threadIdx.x; i < 4096; i += 256) {
        float4 v = p[i];
        s += v.x + v.y + v.z + v.w;
        ss += v.x * v.x + v.y * v.y + v.z * v.z + v.w * v.w;
    }
    for (int w = 1; w < 64; w <<= 1) { s += __shfl_xor(s, w); ss += __shfl_xor(ss, w); }
    __shared__ float rs[4], rss[4];
    int wid = threadIdx.x >> 6;
    if ((threadIdx.x & 63) == 0) { rs[wid] = s; rss[wid] = ss; }
    __syncthreads();
    if (threadIdx.x == 0) {
        float S = rs[0] + rs[1] + rs[2] + rs[3];
        float SS = rss[0] + rss[1] + rss[2] + rss[3];
        float mean = S * (1.f / 16384.f);
        float var = SS * (1.f / 16384.f) - mean * mean;
        stats[bg * 2] = mean;
        stats[bg * 2 + 1] = rsqrtf(var + 1e-5f);
    }
}

// ---------------- kernel 3: GN apply + transpose -> h_t[bn][c] bf16 ----------------
__global__ __launch_bounds__(256) void k_gnapply(const float* __restrict__ x,
                                                 const float* __restrict__ gnw,
                                                 const float* __restrict__ gnb,
                                                 const float* __restrict__ stats,
                                                 unsigned short* __restrict__ h_t) {
    int b = blockIdx.x >> 5, nb = blockIdx.x & 31;
    int n0 = nb * 32;
    __shared__ unsigned short lds[32][520];
    int t = threadIdx.x;
    int f4 = t & 7, c0 = t >> 3;
    for (int c = c0; c < 512; c += 32) {
        int g = c >> 4;
        float mean = stats[(b * 32 + g) * 2], rstd = stats[(b * 32 + g) * 2 + 1];
        float sc = gnw[c] * rstd;
        float sh = gnb[c] - mean * sc;
        float4 v = *(const float4*)(x + ((size_t)(b * 512 + c)) * 1024 + n0 + f4 * 4);
        lds[f4 * 4 + 0][c] = f2bf(v.x * sc + sh);
        lds[f4 * 4 + 1][c] = f2bf(v.y * sc + sh);
        lds[f4 * 4 + 2][c] = f2bf(v.z * sc + sh);
        lds[f4 * 4 + 3][c] = f2bf(v.w * sc + sh);
    }
    __syncthreads();
    int ch = t & 63;
    for (int nl = t >> 6; nl < 32; nl += 4) {
        *(uint4*)(h_t + ((size_t)(b * 1024 + n0 + nl)) * 512 + ch * 8) =
            *(const uint4*)(&lds[nl][ch * 8]);
    }
}

// ---------------- kernel 4/6: BT-GEMM, 128x128 tile, K=512 ----------------
// C[m][n] = sum_k A[m][k] * Bt[n][k]  (both bf16 row-major, K=512)
// mode 0: scatter to Q[bh][n][d], K[bh][m][d], V[bh][d][m] with qkv bias
// mode 1: out[b][oc][n] = x[...] + bias[oc] + C   (fp32)
__global__ __launch_bounds__(256) void k_gemm(const unsigned short* __restrict__ A,
                                              const unsigned short* __restrict__ Bt,
                                              const float* __restrict__ bias, int mode,
                                              unsigned short* __restrict__ Qo,
                                              unsigned short* __restrict__ Ko,
                                              unsigned short* __restrict__ Vo,
                                              const float* __restrict__ xres,
                                              float* __restrict__ out) {
    const int Kd = 512;
    int mt = blockIdx.x, nt = blockIdx.y;
    int t = threadIdx.x, wid = t >> 6, lane = t & 63;
    int lm = lane & 15, q4 = lane >> 4;
    int wm = wid >> 1, wn = wid & 1;
    __shared__ unsigned short ldsA[2][4096];
    __shared__ unsigned short ldsB[2][4096];
    int m0 = mt * 128, n0 = nt * 128;

    auto stage = [&](int buf, int ks) {
        int k0 = ks * 32;
#pragma unroll
        for (int h = 0; h < 2; ++h) {
            int cib = h * 256 + wid * 64;
            int ci = cib + lane;
            int r = ci >> 2;
            int cc = (ci & 3) ^ (r & 3);  // chunk-XOR swizzle (global side)
            gll16(A + (size_t)(m0 + r) * Kd + k0 + cc * 8, &ldsA[buf][cib * 8]);
            gll16(Bt + (size_t)(n0 + r) * Kd + k0 + cc * 8, &ldsB[buf][cib * 8]);
        }
    };

    f32x4 z = {0.f, 0.f, 0.f, 0.f};
    f32x4 acc[4][4];
#pragma unroll
    for (int fi = 0; fi < 4; ++fi)
#pragma unroll
        for (int fj = 0; fj < 4; ++fj) acc[fi][fj] = z;

    stage(0, 0);
    __syncthreads();
    const int NK = 16;
    for (int ks = 0; ks < NK; ++ks) {
        int cur = ks & 1;
        if (ks + 1 < NK) stage(cur ^ 1, ks + 1);
        const unsigned short* lA = ldsA[cur];
        const unsigned short* lB = ldsB[cur];
        s16x8 af[4], bg[4];
#pragma unroll
        for (int fi = 0; fi < 4; ++fi) {
            int rA = wm * 64 + fi * 16 + lm;
            af[fi] = *(const s16x8*)&lA[(rA * 4 + (q4 ^ (lm & 3))) * 8];
        }
#pragma unroll
        for (int fj = 0; fj < 4; ++fj) {
            int rB = wn * 64 + fj * 16 + lm;
            bg[fj] = *(const s16x8*)&lB[(rB * 4 + (q4 ^ (lm & 3))) * 8];
        }
#pragma unroll
        for (int fi = 0; fi < 4; ++fi)
#pragma unroll
            for (int fj = 0; fj < 4; ++fj) acc[fi][fj] = MFMA16(af[fi], bg[fj], acc[fi][fj]);
        __syncthreads();
    }

    if (mode == 0) {
        int part = mt >> 2;  // 0=Q 1=K 2=V (M-tile never straddles parts)
        int head = mt & 3;
        int b = nt >> 3;
        int bh = b * 4 + head;
#pragma unroll
        for (int fi = 0; fi < 4; ++fi) {
            int ddb = wm * 64 + fi * 16 + 4 * q4;  // + i -> d within head
            float bv[4];
#pragma unroll
            for (int i = 0; i < 4; ++i) bv[i] = bias[mt * 128 + ddb + i];
#pragma unroll
            for (int fj = 0; fj < 4; ++fj) {
                int n = ((nt & 7) << 7) + wn * 64 + fj * 16 + lm;
                f32x4 v = acc[fi][fj];
                if (part < 2) {
                    unsigned a0 = (unsigned)f2bf(v[0] + bv[0]) | ((unsigned)f2bf(v[1] + bv[1]) << 16);
                    unsigned a1 = (unsigned)f2bf(v[2] + bv[2]) | ((unsigned)f2bf(v[3] + bv[3]) << 16);
                    unsigned short* dst = (part == 0 ? Qo : Ko) + ((size_t)bh * 1024 + n) * 128 + ddb;
                    uint2 pr; pr.x = a0; pr.y = a1;
                    *(uint2*)dst = pr;
                } else {
#pragma unroll
                    for (int i = 0; i < 4; ++i)
                        Vo[((size_t)bh * 128 + ddb + i) * 1024 + n] = f2bf(v[i] + bv[i]);
                }
            }
        }
    } else {
        int b = nt >> 3;
#pragma unroll
        for (int fi = 0; fi < 4; ++fi) {
            int ocb = m0 + wm * 64 + fi * 16 + 4 * q4;
            float bv[4];
#pragma unroll
            for (int i = 0; i < 4; ++i) bv[i] = bias[ocb + i];
#pragma unroll
            for (int fj = 0; fj < 4; ++fj) {
                int n = ((nt & 7) << 7) + wn * 64 + fj * 16 + lm;
#pragma unroll
                for (int i = 0; i < 4; ++i) {
                    size_t idx = ((size_t)b * 512 + ocb + i) * 1024 + n;
                    out[idx] = xres[idx] + bv[i] + acc[fi][fj][i];
                }
            }
        }
    }
}

// ---------------- kernel 5: flash attention per (bh, q-block of 64) ----------------
__global__ __launch_bounds__(256) void k_attn(const unsigned short* __restrict__ Q,
                                              const unsigned short* __restrict__ K,
                                              const unsigned short* __restrict__ V,
                                              unsigned short* __restrict__ o_t) {
    int bh = blockIdx.y, qb = blockIdx.x;
    int t = threadIdx.x, wid = t >> 6, lane = t & 63;
    int lm = lane & 15, q4 = lane >> 4;
    __shared__ unsigned short kl[32 * 128];   // [m][d] XOR-swizzled
    __shared__ unsigned short vl[128 * 40];   // [d][m] padded 32->40
    __shared__ unsigned short pl[4][16 * 40]; // per-wave P [n][m] padded
    const unsigned short* Qb = Q + ((size_t)bh * 1024 + qb * 64 + wid * 16) * 128;
    const unsigned short* Kb = K + (size_t)bh * 1024 * 128;
    const unsigned short* Vb = V + (size_t)bh * 128 * 1024;
    s16x8 qf[4];
#pragma unroll
    for (int dc = 0; dc < 4; ++dc)
        qf[dc] = *(const s16x8*)&Qb[(size_t)lm * 128 + dc * 32 + q4 * 8];
    f32x4 z = {0.f, 0.f, 0.f, 0.f};
    f32x4 oacc[8];
#pragma unroll
    for (int i = 0; i < 8; ++i) oacc[i] = z;
    float mrow[4] = {-1e30f, -1e30f, -1e30f, -1e30f};
    float lrow[4] = {0.f, 0.f, 0.f, 0.f};
    const float scale = 0.08838834764831845f;  // 128^-0.5

    for (int ms = 0; ms < 32; ++ms) {
        int m0 = ms * 32;
        __syncthreads();
#pragma unroll
        for (int h = 0; h < 2; ++h) {
            int ci = h * 256 + t;
            int mr = ci >> 4, cc = ci & 15;
            *(uint4*)&kl[mr * 128 + (cc ^ (mr & 7)) * 8] =
                *(const uint4*)&Kb[(size_t)(m0 + mr) * 128 + cc * 8];
            int d = ci >> 2, c2 = ci & 3;
            *(uint4*)&vl[d * 40 + c2 * 8] = *(const uint4*)&Vb[(size_t)d * 1024 + m0 + c2 * 8];
        }
        __syncthreads();
        f32x4 s0 = z, s1 = z;
#pragma unroll
        for (int dc = 0; dc < 4; ++dc) {
            s16x8 k0f = *(const s16x8*)&kl[lm * 128 + ((dc * 4 + q4) ^ (lm & 7)) * 8];
            s0 = MFMA16(qf[dc], k0f, s0);
            int mr1 = 16 + lm;
            s16x8 k1f = *(const s16x8*)&kl[mr1 * 128 + ((dc * 4 + q4) ^ (mr1 & 7)) * 8];
            s1 = MFMA16(qf[dc], k1f, s1);
        }
        float tm[4], p0[4], p1[4], rsum[4], corr[4];
#pragma unroll
        for (int i = 0; i < 4; ++i) {
            s0[i] *= scale; s1[i] *= scale;
            tm[i] = fmaxf(s0[i], s1[i]);
        }
#pragma unroll
        for (int w = 1; w < 16; w <<= 1)
#pragma unroll
            for (int i = 0; i < 4; ++i) tm[i] = fmaxf(tm[i], __shfl_xor(tm[i], w));
#pragma unroll
        for (int i = 0; i < 4; ++i) {
            float mn = fmaxf(mrow[i], tm[i]);
            corr[i] = __expf(mrow[i] - mn);
            mrow[i] = mn;
            p0[i] = __expf(s0[i] - mn);
            p1[i] = __expf(s1[i] - mn);
            rsum[i] = p0[i] + p1[i];
        }
#pragma unroll
        for (int w = 1; w < 16; w <<= 1)
#pragma unroll
            for (int i = 0; i < 4; ++i) rsum[i] += __shfl_xor(rsum[i], w);
#pragma unroll
        for (int i = 0; i < 4; ++i) lrow[i] = lrow[i] * corr[i] + rsum[i];
#pragma unroll
        for (int t8 = 0; t8 < 8; ++t8)
#pragma unroll
            for (int i = 0; i < 4; ++i) oacc[t8][i] *= corr[i];
        unsigned short* pw = pl[wid];
#pragma unroll
        for (int i = 0; i < 4; ++i) {
            pw[(4 * q4 + i) * 40 + lm] = f2bf(p0[i]);
            pw[(4 * q4 + i) * 40 + 16 + lm] = f2bf(p1[i]);
        }
        s16x8 pf = *(const s16x8*)&pw[lm * 40 + q4 * 8];
#pragma unroll
        for (int t8 = 0; t8 < 8; ++t8) {
            s16x8 vf = *(const s16x8*)&vl[(t8 * 16 + lm) * 40 + q4 * 8];
            oacc[t8] = MFMA16(pf, vf, oacc[t8]);
        }
    }
    int b = bh >> 2, head = bh & 3;
    float inv[4];
#pragma unroll
    for (int i = 0; i < 4; ++i) inv[i] = 1.f / lrow[i];
#pragma unroll
    for (int t8 = 0; t8 < 8; ++t8)
#pragma unroll
        for (int i = 0; i < 4; ++i) {
            size_t row = (size_t)b * 1024 + qb * 64 + wid * 16 + 4 * q4 + i;
            o_t[row * 512 + head * 128 + t8 * 16 + lm] = f2bf(oacc[t8][i] * inv[i]);
        }
}

extern "C" void kernel_launch(void* const* d_in, const int* in_sizes, int n_in,
                              void* d_out, int out_size, void* d_ws, size_t ws_size,
                              hipStream_t stream) {
    const float* x = (const float*)d_in[0];
    const float* gnw = (const float*)d_in[1];
    const float* gnb = (const float*)d_in[2];
    const float* qkvw = (const float*)d_in[3];
    const float* qkvb = (const float*)d_in[4];
    const float* projw = (const float*)d_in[5];
    const float* projb = (const float*)d_in[6];
    float* out = (float*)d_out;
    char* ws = (char*)d_ws;

    unsigned short* wq = (unsigned short*)(ws);                  // 1536x512 bf16
    unsigned short* wp = (unsigned short*)(ws + 1572864);        // 512x512 bf16
    float* stats = (float*)(ws + 2097152);                       // 512 x {mean,rstd}
    unsigned short* ht = (unsigned short*)(ws + 2101248);        // h_t [16384][512] bf16
    unsigned short* Qb = (unsigned short*)(ws + 18878464);       // [64][1024][128]
    unsigned short* Kb = (unsigned short*)(ws + 35655680);       // [64][1024][128]
    unsigned short* Vb = (unsigned short*)(ws + 52432896);       // [64][128][1024]
    unsigned short* ot = ht;                                     // reuse h_t region

    k_wconv<<<dim3(4096), dim3(256), 0, stream>>>(qkvw, projw, wq);
    k_gnstats<<<dim3(512), dim3(256), 0, stream>>>(x, stats);
    k_gnapply<<<dim3(512), dim3(256), 0, stream>>>(x, gnw, gnb, stats, ht);
    k_gemm<<<dim3(12, 128), dim3(256), 0, stream>>>(wq, ht, qkvb, 0, Qb, Kb, Vb, nullptr, nullptr);
    k_attn<<<dim3(16, 64), dim3(256), 0, stream>>>(Qb, Kb, Vb, ot);
    k_gemm<<<dim3(4, 128), dim3(256), 0, stream>>>(wp, ot, projb, 1, nullptr, nullptr, nullptr, x, out);
}

// Round 2
// 188.066 us; speedup vs baseline: 1.2101x; 1.2101x over previous
//
#include <hip/hip_runtime.h>

typedef __attribute__((ext_vector_type(4))) float f32x4;
typedef __attribute__((ext_vector_type(8))) short s16x8;

#define MFMA16(a, b, c) __builtin_amdgcn_mfma_f32_16x16x32_bf16((a), (b), (c), 0, 0, 0)

__device__ __forceinline__ unsigned short f2bf(float f) {
    union { float f; unsigned u; } v; v.f = f;
    unsigned u = v.u + 0x7FFFu + ((v.u >> 16) & 1u);
    return (unsigned short)(u >> 16);
}

__device__ __forceinline__ unsigned cvtpk(float lo, float hi) {
    unsigned r;
    asm("v_cvt_pk_bf16_f32 %0, %1, %2" : "=v"(r) : "v"(lo), "v"(hi));
    return r;
}

__device__ __forceinline__ void gll16(const unsigned short* g, unsigned short* l) {
    __builtin_amdgcn_global_load_lds((const __attribute__((address_space(1))) void*)g,
                                     (__attribute__((address_space(3))) void*)l, 16, 0, 0);
}

// ---------------- kernel 1: convert qkv_w / proj_w fp32 -> bf16 ----------------
__global__ __launch_bounds__(256) void k_wconv(const float* __restrict__ qkv_w,
                                               const float* __restrict__ proj_w,
                                               unsigned short* __restrict__ wout) {
    int i = blockIdx.x * 256 + threadIdx.x;
    const int NQ = 3 * 512 * 512;
    float v = (i < NQ) ? qkv_w[i] : proj_w[i - NQ];
    wout[i] = f2bf(v);
}

// ---------------- kernel 2: group-norm stats (mean, rstd) per (b,g) ----------------
__global__ __launch_bounds__(256) void k_gnstats(const float* __restrict__ x,
                                                 float* __restrict__ stats) {
    int bg = blockIdx.x; // 0..511, group block is 16*1024 contiguous floats
    const float4* p = (const float4*)(x + (size_t)bg * 16384);
    float s = 0.f, ss = 0.f;
    for (int i = threadIdx.x; i < 4096; i += 256) {
        float4 v = p[i];
        s += v.x + v.y + v.z + v.w;
        ss += v.x * v.x + v.y * v.y + v.z * v.z + v.w * v.w;
    }
    for (int w = 1; w < 64; w <<= 1) { s += __shfl_xor(s, w); ss += __shfl_xor(ss, w); }
    __shared__ float rs[4], rss[4];
    int wid = threadIdx.x >> 6;
    if ((threadIdx.x & 63) == 0) { rs[wid] = s; rss[wid] = ss; }
    __syncthreads();
    if (threadIdx.x == 0) {
        float S = rs[0] + rs[1] + rs[2] + rs[3];
        float SS = rss[0] + rss[1] + rss[2] + rss[3];
        float mean = S * (1.f / 16384.f);
        float var = SS * (1.f / 16384.f) - mean * mean;
        stats[bg * 2] = mean;
        stats[bg * 2 + 1] = rsqrtf(var + 1e-5f);
    }
}

// ---------------- kernel 3: GN apply + transpose -> h_t[bn][c] bf16 ----------------
__global__ __launch_bounds__(256) void k_gnapply(const float* __restrict__ x,
                                                 const float* __restrict__ gnw,
                                                 const float* __restrict__ gnb,
                                                 const float* __restrict__ stats,
                                                 unsigned short* __restrict__ h_t) {
    int b = blockIdx.x >> 5, nb = blockIdx.x & 31;
    int n0 = nb * 32;
    __shared__ unsigned short lds[32][520];
    int t = threadIdx.x;
    int f4 = t & 7, c0 = t >> 3;
    for (int c = c0; c < 512; c += 32) {
        int g = c >> 4;
        float mean = stats[(b * 32 + g) * 2], rstd = stats[(b * 32 + g) * 2 + 1];
        float sc = gnw[c] * rstd;
        float sh = gnb[c] - mean * sc;
        float4 v = *(const float4*)(x + ((size_t)(b * 512 + c)) * 1024 + n0 + f4 * 4);
        lds[f4 * 4 + 0][c] = f2bf(v.x * sc + sh);
        lds[f4 * 4 + 1][c] = f2bf(v.y * sc + sh);
        lds[f4 * 4 + 2][c] = f2bf(v.z * sc + sh);
        lds[f4 * 4 + 3][c] = f2bf(v.w * sc + sh);
    }
    __syncthreads();
    int ch = t & 63;
    for (int nl = t >> 6; nl < 32; nl += 4) {
        *(uint4*)(h_t + ((size_t)(b * 1024 + n0 + nl)) * 512 + ch * 8) =
            *(const uint4*)(&lds[nl][ch * 8]);
    }
}

// ---------------- kernel 4/6: BT-GEMM, 128x128 tile, K=512 ----------------
// C[m][n] = sum_k A[m][k] * Bt[n][k]  (both bf16 row-major, K=512)
// mode 0: scatter to Q[bh][n][d] (pre-scaled), K[bh][m][d], V[bh][d][m-permuted]
// mode 1: out[b][oc][n] = x[...] + bias[oc] + C   (fp32)
__global__ __launch_bounds__(256) void k_gemm(const unsigned short* __restrict__ A,
                                              const unsigned short* __restrict__ Bt,
                                              const float* __restrict__ bias, int mode,
                                              unsigned short* __restrict__ Qo,
                                              unsigned short* __restrict__ Ko,
                                              unsigned short* __restrict__ Vo,
                                              const float* __restrict__ xres,
                                              float* __restrict__ out) {
    const int Kd = 512;
    int mt = blockIdx.x, nt = blockIdx.y;
    int t = threadIdx.x, wid = t >> 6, lane = t & 63;
    int lm = lane & 15, q4 = lane >> 4;
    int wm = wid >> 1, wn = wid & 1;
    __shared__ unsigned short ldsA[2][4096];
    __shared__ unsigned short ldsB[2][4096];
    int m0 = mt * 128, n0 = nt * 128;

    auto stage = [&](int buf, int ks) {
        int k0 = ks * 32;
#pragma unroll
        for (int h = 0; h < 2; ++h) {
            int cib = h * 256 + wid * 64;
            int ci = cib + lane;
            int r = ci >> 2;
            int cc = (ci & 3) ^ (r & 3);  // chunk-XOR swizzle (global side)
            gll16(A + (size_t)(m0 + r) * Kd + k0 + cc * 8, &ldsA[buf][cib * 8]);
            gll16(Bt + (size_t)(n0 + r) * Kd + k0 + cc * 8, &ldsB[buf][cib * 8]);
        }
    };

    f32x4 z = {0.f, 0.f, 0.f, 0.f};
    f32x4 acc[4][4];
#pragma unroll
    for (int fi = 0; fi < 4; ++fi)
#pragma unroll
        for (int fj = 0; fj < 4; ++fj) acc[fi][fj] = z;

    stage(0, 0);
    __syncthreads();
    const int NK = 16;
    for (int ks = 0; ks < NK; ++ks) {
        int cur = ks & 1;
        if (ks + 1 < NK) stage(cur ^ 1, ks + 1);
        const unsigned short* lA = ldsA[cur];
        const unsigned short* lB = ldsB[cur];
        s16x8 af[4], bg[4];
#pragma unroll
        for (int fi = 0; fi < 4; ++fi) {
            int rA = wm * 64 + fi * 16 + lm;
            af[fi] = *(const s16x8*)&lA[(rA * 4 + (q4 ^ (lm & 3))) * 8];
        }
#pragma unroll
        for (int fj = 0; fj < 4; ++fj) {
            int rB = wn * 64 + fj * 16 + lm;
            bg[fj] = *(const s16x8*)&lB[(rB * 4 + (q4 ^ (lm & 3))) * 8];
        }
#pragma unroll
        for (int fi = 0; fi < 4; ++fi)
#pragma unroll
            for (int fj = 0; fj < 4; ++fj) acc[fi][fj] = MFMA16(af[fi], bg[fj], acc[fi][fj]);
        __syncthreads();
    }

    if (mode == 0) {
        int part = mt >> 2;  // 0=Q 1=K 2=V (M-tile never straddles parts)
        int head = mt & 3;
        int b = nt >> 3;
        int bh = b * 4 + head;
        const float qscale = 0.08838834764831845f;  // 128^-0.5, folded into Q
#pragma unroll
        for (int fi = 0; fi < 4; ++fi) {
            int ddb = wm * 64 + fi * 16 + 4 * q4;  // + i -> d within head
            float bv[4];
#pragma unroll
            for (int i = 0; i < 4; ++i) bv[i] = bias[mt * 128 + ddb + i];
#pragma unroll
            for (int fj = 0; fj < 4; ++fj) {
                int n = ((nt & 7) << 7) + wn * 64 + fj * 16 + lm;
                f32x4 v = acc[fi][fj];
                if (part == 0) {
                    uint2 pr;
                    pr.x = cvtpk((v[0] + bv[0]) * qscale, (v[1] + bv[1]) * qscale);
                    pr.y = cvtpk((v[2] + bv[2]) * qscale, (v[3] + bv[3]) * qscale);
                    *(uint2*)(Qo + ((size_t)bh * 1024 + n) * 128 + ddb) = pr;
                } else if (part == 1) {
                    uint2 pr;
                    pr.x = cvtpk(v[0] + bv[0], v[1] + bv[1]);
                    pr.y = cvtpk(v[2] + bv[2], v[3] + bv[3]);
                    *(uint2*)(Ko + ((size_t)bh * 1024 + n) * 128 + ddb) = pr;
                } else {
                    // permute m within each 32-block so attn's PV A-frag k-order
                    // matches the lane-local P register order (perm(8a+j))
                    int r = (fj & 1) * 16 + lm;
                    int kidx = (lm >> 2) * 8 + (fj & 1) * 4 + (lm & 3);
                    int np = n - r + kidx;
#pragma unroll
                    for (int i = 0; i < 4; ++i)
                        Vo[((size_t)bh * 128 + ddb + i) * 1024 + np] = f2bf(v[i] + bv[i]);
                }
            }
        }
    } else {
        int b = nt >> 3;
#pragma unroll
        for (int fi = 0; fi < 4; ++fi) {
            int ocb = m0 + wm * 64 + fi * 16 + 4 * q4;
            float bv[4];
#pragma unroll
            for (int i = 0; i < 4; ++i) bv[i] = bias[ocb + i];
#pragma unroll
            for (int fj = 0; fj < 4; ++fj) {
                int n = ((nt & 7) << 7) + wn * 64 + fj * 16 + lm;
#pragma unroll
                for (int i = 0; i < 4; ++i) {
                    size_t idx = ((size_t)b * 512 + ocb + i) * 1024 + n;
                    out[idx] = xres[idx] + bv[i] + acc[fi][fj][i];
                }
            }
        }
    }
}

// ---------------- kernel 5: flash attention, swapped-operand softmax ----------------
// Per wave: 16 queries (n = qb*64 + wid*16 + lm). S^T = mfma(K,Q): lane owns
// P[m-slice][n=lm] in registers -> in-register row reduce + cvt_pk -> PV B-frag
// directly (V stored m-permuted). Double-buffered gll16 staging, counted vmcnt.
__global__ __launch_bounds__(256) void k_attn(const unsigned short* __restrict__ Q,
                                              const unsigned short* __restrict__ K,
                                              const unsigned short* __restrict__ V,
                                              unsigned short* __restrict__ o_t) {
    int bh = blockIdx.y, qb = blockIdx.x;
    int t = threadIdx.x, wid = t >> 6, lane = t & 63;
    int lm = lane & 15, q4 = lane >> 4;
    __shared__ unsigned short ldsK[2][4096];  // [m=32][d=128], chunk^(m&7) swizzle
    __shared__ unsigned short ldsV[2][4096];  // [d=128][k=32], chunk^((d>>1)&3) swizzle
    const unsigned short* Qg = Q + ((size_t)bh * 1024 + qb * 64 + wid * 16) * 128;
    const unsigned short* Kg = K + (size_t)bh * 1024 * 128;
    const unsigned short* Vg = V + (size_t)bh * 128 * 1024;

    s16x8 qf[4];
#pragma unroll
    for (int dc = 0; dc < 4; ++dc)
        qf[dc] = *(const s16x8*)&Qg[lm * 128 + dc * 32 + q4 * 8];

    f32x4 z = {0.f, 0.f, 0.f, 0.f};
    f32x4 oacc[8];
#pragma unroll
    for (int i = 0; i < 8; ++i) oacc[i] = z;
    float mrow = -1e30f, lrow = 0.f;

    auto stageK = [&](int buf, int m0) {
#pragma unroll
        for (int h = 0; h < 2; ++h) {
            int cib = h * 256 + wid * 64;
            int ci = cib + lane;
            int mr = ci >> 4, cl = ci & 15;
            int cs = cl ^ (mr & 7);
            gll16(Kg + (size_t)(m0 + mr) * 128 + cs * 8, &ldsK[buf][cib * 8]);
        }
    };
    auto stageV = [&](int buf, int m0) {
#pragma unroll
        for (int h = 0; h < 2; ++h) {
            int cib = h * 256 + wid * 64;
            int ci = cib + lane;
            int d = ci >> 2, kc = ci & 3;
            int ks = kc ^ ((d >> 1) & 3);
            gll16(Vg + (size_t)d * 1024 + m0 + ks * 8, &ldsV[buf][cib * 8]);
        }
    };

    stageK(0, 0);
    stageV(0, 0);

    for (int ms = 0; ms < 32; ++ms) {
        int cur = ms & 1;
        if (ms < 31) {
            stageK(cur ^ 1, (ms + 1) * 32);
            stageV(cur ^ 1, (ms + 1) * 32);
            asm volatile("s_waitcnt vmcnt(4)" ::: "memory");
        } else {
            asm volatile("s_waitcnt vmcnt(0)" ::: "memory");
        }
        __builtin_amdgcn_s_barrier();
        const unsigned short* lK = ldsK[cur];
        const unsigned short* lV = ldsV[cur];

        f32x4 s0 = z, s1 = z;
#pragma unroll
        for (int dc = 0; dc < 4; ++dc) {
            int sw = ((dc * 4 + q4) ^ (lm & 7)) * 8;
            s16x8 k0 = *(const s16x8*)&lK[lm * 128 + sw];
            s16x8 k1 = *(const s16x8*)&lK[(16 + lm) * 128 + sw];
            s0 = MFMA16(k0, qf[dc], s0);
            s1 = MFMA16(k1, qf[dc], s1);
        }
        // row reduce over m: 8 in-reg + 2 shfl (q4 replicas)
        float tm = fmaxf(fmaxf(fmaxf(s0[0], s0[1]), fmaxf(s0[2], s0[3])),
                         fmaxf(fmaxf(s1[0], s1[1]), fmaxf(s1[2], s1[3])));
        tm = fmaxf(tm, __shfl_xor(tm, 16));
        tm = fmaxf(tm, __shfl_xor(tm, 32));
        if (!__all(tm <= mrow + 8.f)) {  // defer-max (T13)
            float mn = fmaxf(mrow, tm);
            float corr = __expf(mrow - mn);
            lrow *= corr;
#pragma unroll
            for (int t8 = 0; t8 < 8; ++t8)
#pragma unroll
                for (int i = 0; i < 4; ++i) oacc[t8][i] *= corr;
            mrow = mn;
        }
        float p0[4], p1[4];
        float rs = 0.f;
#pragma unroll
        for (int i = 0; i < 4; ++i) {
            p0[i] = __expf(s0[i] - mrow);
            p1[i] = __expf(s1[i] - mrow);
            rs += p0[i] + p1[i];
        }
        rs += __shfl_xor(rs, 16);
        rs += __shfl_xor(rs, 32);
        lrow += rs;
        union { s16x8 v; unsigned u[4]; } pb;
        pb.u[0] = cvtpk(p0[0], p0[1]);
        pb.u[1] = cvtpk(p0[2], p0[3]);
        pb.u[2] = cvtpk(p1[0], p1[1]);
        pb.u[3] = cvtpk(p1[2], p1[3]);
#pragma unroll
        for (int t8 = 0; t8 < 8; ++t8) {
            int r = t8 * 16 + lm;
            s16x8 vf = *(const s16x8*)&lV[r * 32 + ((q4 ^ ((lm >> 1) & 3)) * 8)];
            oacc[t8] = MFMA16(vf, pb.v, oacc[t8]);
        }
        __builtin_amdgcn_s_barrier();
    }

    float inv = 1.f / lrow;
    int b = bh >> 2, head = bh & 3;
    size_t row = (size_t)b * 1024 + qb * 64 + wid * 16 + lm;
    unsigned short* dst = o_t + row * 512 + head * 128;
#pragma unroll
    for (int t8 = 0; t8 < 8; ++t8) {
        uint2 pr;
        pr.x = cvtpk(oacc[t8][0] * inv, oacc[t8][1] * inv);
        pr.y = cvtpk(oacc[t8][2] * inv, oacc[t8][3] * inv);
        *(uint2*)&dst[t8 * 16 + q4 * 4] = pr;
    }
}

extern "C" void kernel_launch(void* const* d_in, const int* in_sizes, int n_in,
                              void* d_out, int out_size, void* d_ws, size_t ws_size,
                              hipStream_t stream) {
    const float* x = (const float*)d_in[0];
    const float* gnw = (const float*)d_in[1];
    const float* gnb = (const float*)d_in[2];
    const float* qkvw = (const float*)d_in[3];
    const float* qkvb = (const float*)d_in[4];
    const float* projw = (const float*)d_in[5];
    const float* projb = (const float*)d_in[6];
    float* out = (float*)d_out;
    char* ws = (char*)d_ws;

    unsigned short* wq = (unsigned short*)(ws);                  // 1536x512 bf16
    unsigned short* wp = (unsigned short*)(ws + 1572864);        // 512x512 bf16
    float* stats = (float*)(ws + 2097152);                       // 512 x {mean,rstd}
    unsigned short* ht = (unsigned short*)(ws + 2101248);        // h_t [16384][512] bf16
    unsigned short* Qb = (unsigned short*)(ws + 18878464);       // [64][1024][128]
    unsigned short* Kb = (unsigned short*)(ws + 35655680);       // [64][1024][128]
    unsigned short* Vb = (unsigned short*)(ws + 52432896);       // [64][128][1024] (m-permuted)
    unsigned short* ot = ht;                                     // reuse h_t region

    k_wconv<<<dim3(4096), dim3(256), 0, stream>>>(qkvw, projw, wq);
    k_gnstats<<<dim3(512), dim3(256), 0, stream>>>(x, stats);
    k_gnapply<<<dim3(512), dim3(256), 0, stream>>>(x, gnw, gnb, stats, ht);
    k_gemm<<<dim3(12, 128), dim3(256), 0, stream>>>(wq, ht, qkvb, 0, Qb, Kb, Vb, nullptr, nullptr);
    k_attn<<<dim3(16, 64), dim3(256), 0, stream>>>(Qb, Kb, Vb, ot);
    k_gemm<<<dim3(4, 128), dim3(256), 0, stream>>>(wp, ot, projb, 1, nullptr, nullptr, nullptr, x, out);
}

// Round 3
// 148.300 us; speedup vs baseline: 1.5346x; 1.2681x over previous
//
#include <hip/hip_runtime.h>

typedef __attribute__((ext_vector_type(4))) float f32x4;
typedef __attribute__((ext_vector_type(8))) short s16x8;

#define MFMA16(a, b, c) __builtin_amdgcn_mfma_f32_16x16x32_bf16((a), (b), (c), 0, 0, 0)

__device__ __forceinline__ unsigned short f2bf(float f) {
    union { float f; unsigned u; } v; v.f = f;
    unsigned u = v.u + 0x7FFFu + ((v.u >> 16) & 1u);
    return (unsigned short)(u >> 16);
}

__device__ __forceinline__ unsigned cvtpk(float lo, float hi) {
    unsigned r;
    asm("v_cvt_pk_bf16_f32 %0, %1, %2" : "=v"(r) : "v"(lo), "v"(hi));
    return r;
}

__device__ __forceinline__ float exp2f_fast(float x) {
    float r;
    asm("v_exp_f32 %0, %1" : "=v"(r) : "v"(x));
    return r;
}

__device__ __forceinline__ void gll16(const unsigned short* g, unsigned short* l) {
    __builtin_amdgcn_global_load_lds((const __attribute__((address_space(1))) void*)g,
                                     (__attribute__((address_space(3))) void*)l, 16, 0, 0);
}

// ---------------- kernel 1: convert qkv_w / proj_w fp32 -> bf16 ----------------
__global__ __launch_bounds__(256) void k_wconv(const float* __restrict__ qkv_w,
                                               const float* __restrict__ proj_w,
                                               unsigned short* __restrict__ wout) {
    int i = blockIdx.x * 256 + threadIdx.x;
    const int NQ = 3 * 512 * 512;
    float v = (i < NQ) ? qkv_w[i] : proj_w[i - NQ];
    wout[i] = f2bf(v);
}

// ---------------- kernel 2: group-norm stats (mean, rstd) per (b,g) ----------------
__global__ __launch_bounds__(256) void k_gnstats(const float* __restrict__ x,
                                                 float* __restrict__ stats) {
    int bg = blockIdx.x; // 0..511, group block is 16*1024 contiguous floats
    const float4* p = (const float4*)(x + (size_t)bg * 16384);
    float s = 0.f, ss = 0.f;
    for (int i = threadIdx.x; i < 4096; i += 256) {
        float4 v = p[i];
        s += v.x + v.y + v.z + v.w;
        ss += v.x * v.x + v.y * v.y + v.z * v.z + v.w * v.w;
    }
    for (int w = 1; w < 64; w <<= 1) { s += __shfl_xor(s, w); ss += __shfl_xor(ss, w); }
    __shared__ float rs[4], rss[4];
    int wid = threadIdx.x >> 6;
    if ((threadIdx.x & 63) == 0) { rs[wid] = s; rss[wid] = ss; }
    __syncthreads();
    if (threadIdx.x == 0) {
        float S = rs[0] + rs[1] + rs[2] + rs[3];
        float SS = rss[0] + rss[1] + rss[2] + rss[3];
        float mean = S * (1.f / 16384.f);
        float var = SS * (1.f / 16384.f) - mean * mean;
        stats[bg * 2] = mean;
        stats[bg * 2 + 1] = rsqrtf(var + 1e-5f);
    }
}

// ---------------- kernel 3: GN apply + transpose -> h_t[bn][c] bf16 ----------------
__global__ __launch_bounds__(256) void k_gnapply(const float* __restrict__ x,
                                                 const float* __restrict__ gnw,
                                                 const float* __restrict__ gnb,
                                                 const float* __restrict__ stats,
                                                 unsigned short* __restrict__ h_t) {
    int b = blockIdx.x >> 5, nb = blockIdx.x & 31;
    int n0 = nb * 32;
    __shared__ unsigned short lds[32][520];
    int t = threadIdx.x;
    int f4 = t & 7, c0 = t >> 3;
    for (int c = c0; c < 512; c += 32) {
        int g = c >> 4;
        float mean = stats[(b * 32 + g) * 2], rstd = stats[(b * 32 + g) * 2 + 1];
        float sc = gnw[c] * rstd;
        float sh = gnb[c] - mean * sc;
        float4 v = *(const float4*)(x + ((size_t)(b * 512 + c)) * 1024 + n0 + f4 * 4);
        lds[f4 * 4 + 0][c] = f2bf(v.x * sc + sh);
        lds[f4 * 4 + 1][c] = f2bf(v.y * sc + sh);
        lds[f4 * 4 + 2][c] = f2bf(v.z * sc + sh);
        lds[f4 * 4 + 3][c] = f2bf(v.w * sc + sh);
    }
    __syncthreads();
    int ch = t & 63;
    for (int nl = t >> 6; nl < 32; nl += 4) {
        *(uint4*)(h_t + ((size_t)(b * 1024 + n0 + nl)) * 512 + ch * 8) =
            *(const uint4*)(&lds[nl][ch * 8]);
    }
}

// ---------------- kernel 4/6: BT-GEMM, 128x128 tile, K=512 ----------------
// C[m][n] = sum_k A[m][k] * Bt[n][k]  (both bf16 row-major, K=512)
// mode 0: scatter to Q[bh][n][d] (pre-scaled by 1/sqrt(d)*log2e), K[bh][m][d],
//         V[bh][d][m-permuted]
// mode 1: out[b][oc][n] = x[...] + bias[oc] + C   (fp32)
__global__ __launch_bounds__(256) void k_gemm(const unsigned short* __restrict__ A,
                                              const unsigned short* __restrict__ Bt,
                                              const float* __restrict__ bias, int mode,
                                              unsigned short* __restrict__ Qo,
                                              unsigned short* __restrict__ Ko,
                                              unsigned short* __restrict__ Vo,
                                              const float* __restrict__ xres,
                                              float* __restrict__ out) {
    const int Kd = 512;
    int mt = blockIdx.x, nt = blockIdx.y;
    int t = threadIdx.x, wid = t >> 6, lane = t & 63;
    int lm = lane & 15, q4 = lane >> 4;
    int wm = wid >> 1, wn = wid & 1;
    __shared__ unsigned short ldsA[2][4096];
    __shared__ unsigned short ldsB[2][4096];
    int m0 = mt * 128, n0 = nt * 128;

    auto stage = [&](int buf, int ks) {
        int k0 = ks * 32;
#pragma unroll
        for (int h = 0; h < 2; ++h) {
            int cib = h * 256 + wid * 64;
            int ci = cib + lane;
            int r = ci >> 2;
            int cc = (ci & 3) ^ (r & 3);  // chunk-XOR swizzle (global side)
            gll16(A + (size_t)(m0 + r) * Kd + k0 + cc * 8, &ldsA[buf][cib * 8]);
            gll16(Bt + (size_t)(n0 + r) * Kd + k0 + cc * 8, &ldsB[buf][cib * 8]);
        }
    };

    f32x4 z = {0.f, 0.f, 0.f, 0.f};
    f32x4 acc[4][4];
#pragma unroll
    for (int fi = 0; fi < 4; ++fi)
#pragma unroll
        for (int fj = 0; fj < 4; ++fj) acc[fi][fj] = z;

    stage(0, 0);
    __syncthreads();
    const int NK = 16;
    for (int ks = 0; ks < NK; ++ks) {
        int cur = ks & 1;
        if (ks + 1 < NK) stage(cur ^ 1, ks + 1);
        const unsigned short* lA = ldsA[cur];
        const unsigned short* lB = ldsB[cur];
        s16x8 af[4], bg[4];
#pragma unroll
        for (int fi = 0; fi < 4; ++fi) {
            int rA = wm * 64 + fi * 16 + lm;
            af[fi] = *(const s16x8*)&lA[(rA * 4 + (q4 ^ (lm & 3))) * 8];
        }
#pragma unroll
        for (int fj = 0; fj < 4; ++fj) {
            int rB = wn * 64 + fj * 16 + lm;
            bg[fj] = *(const s16x8*)&lB[(rB * 4 + (q4 ^ (lm & 3))) * 8];
        }
#pragma unroll
        for (int fi = 0; fi < 4; ++fi)
#pragma unroll
            for (int fj = 0; fj < 4; ++fj) acc[fi][fj] = MFMA16(af[fi], bg[fj], acc[fi][fj]);
        __syncthreads();
    }

    if (mode == 0) {
        int part = mt >> 2;  // 0=Q 1=K 2=V (M-tile never straddles parts)
        int head = mt & 3;
        int b = nt >> 3;
        int bh = b * 4 + head;
        const float qscale = 0.08838834764831845f * 1.4426950408889634f;  // 1/sqrt(128)*log2e
#pragma unroll
        for (int fi = 0; fi < 4; ++fi) {
            int ddb = wm * 64 + fi * 16 + 4 * q4;  // + i -> d within head
            float bv[4];
#pragma unroll
            for (int i = 0; i < 4; ++i) bv[i] = bias[mt * 128 + ddb + i];
#pragma unroll
            for (int fj = 0; fj < 4; ++fj) {
                int n = ((nt & 7) << 7) + wn * 64 + fj * 16 + lm;
                f32x4 v = acc[fi][fj];
                if (part == 0) {
                    uint2 pr;
                    pr.x = cvtpk((v[0] + bv[0]) * qscale, (v[1] + bv[1]) * qscale);
                    pr.y = cvtpk((v[2] + bv[2]) * qscale, (v[3] + bv[3]) * qscale);
                    *(uint2*)(Qo + ((size_t)bh * 1024 + n) * 128 + ddb) = pr;
                } else if (part == 1) {
                    uint2 pr;
                    pr.x = cvtpk(v[0] + bv[0], v[1] + bv[1]);
                    pr.y = cvtpk(v[2] + bv[2], v[3] + bv[3]);
                    *(uint2*)(Ko + ((size_t)bh * 1024 + n) * 128 + ddb) = pr;
                } else {
                    // permute m within each 32-block so attn's PV A-frag k-order
                    // matches the lane-local P register order (perm(8a+j))
                    int r = (fj & 1) * 16 + lm;
                    int kidx = (lm >> 2) * 8 + (fj & 1) * 4 + (lm & 3);
                    int np = n - r + kidx;
#pragma unroll
                    for (int i = 0; i < 4; ++i)
                        Vo[((size_t)bh * 128 + ddb + i) * 1024 + np] = f2bf(v[i] + bv[i]);
                }
            }
        }
    } else {
        int b = nt >> 3;
#pragma unroll
        for (int fi = 0; fi < 4; ++fi) {
            int ocb = m0 + wm * 64 + fi * 16 + 4 * q4;
            float bv[4];
#pragma unroll
            for (int i = 0; i < 4; ++i) bv[i] = bias[ocb + i];
#pragma unroll
            for (int fj = 0; fj < 4; ++fj) {
                int n = ((nt & 7) << 7) + wn * 64 + fj * 16 + lm;
#pragma unroll
                for (int i = 0; i < 4; ++i) {
                    size_t idx = ((size_t)b * 512 + ocb + i) * 1024 + n;
                    out[idx] = xres[idx] + bv[i] + acc[fi][fj][i];
                }
            }
        }
    }
}

// ---------------- kernel 5: flash attention, 32 queries/wave ----------------
// S^T = mfma(K,Q): lane owns P[8 m-slots][query lm] (+ query 16+lm) in regs.
// exp2 domain (log2e folded into Q). Deferred l-sum (one reduce at end).
// Defer-max on LOCAL max via __all. V stored m-permuted feeds PV directly.
__global__ __launch_bounds__(256, 2) void k_attn(const unsigned short* __restrict__ Q,
                                                 const unsigned short* __restrict__ K,
                                                 const unsigned short* __restrict__ V,
                                                 unsigned short* __restrict__ o_t) {
    int id = blockIdx.y * 8 + blockIdx.x;
    int bh = (id & 7) + ((id >> 6) << 3);   // XCD swizzle: all 8 q-blocks of a bh
    int qb = (id >> 3) & 7;                 // land on one XCD for K/V L2 reuse
    int t = threadIdx.x, wid = t >> 6, lane = t & 63;
    int lm = lane & 15, q4 = lane >> 4;
    __shared__ unsigned short ldsK[2][4096];  // [m=32][d=128], chunk^(m&7) swizzle
    __shared__ unsigned short ldsV[2][4096];  // [d=128][k=32], chunk^((d>>1)&3) swizzle
    const unsigned short* Qg = Q + ((size_t)bh * 1024 + qb * 128 + wid * 32) * 128;
    const unsigned short* Kg = K + (size_t)bh * 1024 * 128;
    const unsigned short* Vg = V + (size_t)bh * 128 * 1024;

    s16x8 qf0[4], qf1[4];
#pragma unroll
    for (int dc = 0; dc < 4; ++dc) {
        qf0[dc] = *(const s16x8*)&Qg[lm * 128 + dc * 32 + q4 * 8];
        qf1[dc] = *(const s16x8*)&Qg[(16 + lm) * 128 + dc * 32 + q4 * 8];
    }

    // hoisted staging pointers (strength-reduced per-iter increments)
    const unsigned short* gk[2];
    const unsigned short* gv[2];
    unsigned short* lkd[2][2];
    unsigned short* lvd[2][2];
#pragma unroll
    for (int h = 0; h < 2; ++h) {
        int cib = h * 256 + wid * 64;
        int ci = cib + lane;
        int mr = ci >> 4, cl = ci & 15;
        gk[h] = Kg + mr * 128 + (cl ^ (mr & 7)) * 8;
        int d = ci >> 2, kc = ci & 3;
        gv[h] = Vg + (size_t)d * 1024 + (kc ^ ((d >> 1) & 3)) * 8;
        lkd[0][h] = &ldsK[0][cib * 8];
        lkd[1][h] = &ldsK[1][cib * 8];
        lvd[0][h] = &ldsV[0][cib * 8];
        lvd[1][h] = &ldsV[1][cib * 8];
    }
    gll16(gk[0], lkd[0][0]); gll16(gk[1], lkd[0][1]);
    gll16(gv[0], lvd[0][0]); gll16(gv[1], lvd[0][1]);
    gk[0] += 4096; gk[1] += 4096; gv[0] += 32; gv[1] += 32;

    f32x4 z = {0.f, 0.f, 0.f, 0.f};
    f32x4 oa[8], ob[8];
#pragma unroll
    for (int i = 0; i < 8; ++i) { oa[i] = z; ob[i] = z; }
    float mra = -1e30f, mrb = -1e30f, lpa = 0.f, lpb = 0.f;

    for (int ms = 0; ms < 32; ++ms) {
        int cur = ms & 1;
        if (ms < 31) {
            int nb = cur ^ 1;
            gll16(gk[0], lkd[nb][0]); gll16(gk[1], lkd[nb][1]);
            gll16(gv[0], lvd[nb][0]); gll16(gv[1], lvd[nb][1]);
            gk[0] += 4096; gk[1] += 4096; gv[0] += 32; gv[1] += 32;
            asm volatile("s_waitcnt vmcnt(4)" ::: "memory");
        } else {
            asm volatile("s_waitcnt vmcnt(0)" ::: "memory");
        }
        __builtin_amdgcn_s_barrier();
        const unsigned short* lK = ldsK[cur];
        const unsigned short* lV = ldsV[cur];

        f32x4 s0a = z, s0b = z, s1a = z, s1b = z;
        __builtin_amdgcn_s_setprio(1);
#pragma unroll
        for (int dc = 0; dc < 4; ++dc) {
            int sw = ((dc * 4 + q4) ^ (lm & 7)) * 8;
            s16x8 k0 = *(const s16x8*)&lK[lm * 128 + sw];
            s16x8 k1 = *(const s16x8*)&lK[(16 + lm) * 128 + sw];
            s0a = MFMA16(k0, qf0[dc], s0a);
            s0b = MFMA16(k0, qf1[dc], s0b);
            s1a = MFMA16(k1, qf0[dc], s1a);
            s1b = MFMA16(k1, qf1[dc], s1b);
        }
        __builtin_amdgcn_s_setprio(0);

        float tma = fmaxf(fmaxf(fmaxf(s0a[0], s0a[1]), fmaxf(s0a[2], s0a[3])),
                          fmaxf(fmaxf(s1a[0], s1a[1]), fmaxf(s1a[2], s1a[3])));
        float tmb = fmaxf(fmaxf(fmaxf(s0b[0], s0b[1]), fmaxf(s0b[2], s0b[3])),
                          fmaxf(fmaxf(s1b[0], s1b[1]), fmaxf(s1b[2], s1b[3])));
        if (!__all(tma <= mra + 8.f && tmb <= mrb + 8.f)) {  // defer-max (T13)
            tma = fmaxf(tma, __shfl_xor(tma, 16));
            tma = fmaxf(tma, __shfl_xor(tma, 32));
            tmb = fmaxf(tmb, __shfl_xor(tmb, 16));
            tmb = fmaxf(tmb, __shfl_xor(tmb, 32));
            float mna = fmaxf(mra, tma), mnb = fmaxf(mrb, tmb);
            float ca = exp2f_fast(mra - mna), cb = exp2f_fast(mrb - mnb);
            lpa *= ca; lpb *= cb;
#pragma unroll
            for (int t8 = 0; t8 < 8; ++t8)
#pragma unroll
                for (int i = 0; i < 4; ++i) { oa[t8][i] *= ca; ob[t8][i] *= cb; }
            mra = mna; mrb = mnb;
        }
        float pa[8], pb[8];
#pragma unroll
        for (int i = 0; i < 4; ++i) {
            pa[i]     = exp2f_fast(s0a[i] - mra);
            pa[4 + i] = exp2f_fast(s1a[i] - mra);
            pb[i]     = exp2f_fast(s0b[i] - mrb);
            pb[4 + i] = exp2f_fast(s1b[i] - mrb);
        }
#pragma unroll
        for (int i = 0; i < 8; ++i) { lpa += pa[i]; lpb += pb[i]; }
        union { s16x8 v; unsigned u[4]; } fa, fb;
        fa.u[0] = cvtpk(pa[0], pa[1]); fa.u[1] = cvtpk(pa[2], pa[3]);
        fa.u[2] = cvtpk(pa[4], pa[5]); fa.u[3] = cvtpk(pa[6], pa[7]);
        fb.u[0] = cvtpk(pb[0], pb[1]); fb.u[1] = cvtpk(pb[2], pb[3]);
        fb.u[2] = cvtpk(pb[4], pb[5]); fb.u[3] = cvtpk(pb[6], pb[7]);

        __builtin_amdgcn_s_setprio(1);
#pragma unroll
        for (int t8 = 0; t8 < 8; ++t8) {
            int r = t8 * 16 + lm;
            s16x8 vf = *(const s16x8*)&lV[r * 32 + ((q4 ^ ((lm >> 1) & 3)) * 8)];
            oa[t8] = MFMA16(vf, fa.v, oa[t8]);
            ob[t8] = MFMA16(vf, fb.v, ob[t8]);
        }
        __builtin_amdgcn_s_setprio(0);
        __builtin_amdgcn_s_barrier();
    }

    lpa += __shfl_xor(lpa, 16); lpa += __shfl_xor(lpa, 32);
    lpb += __shfl_xor(lpb, 16); lpb += __shfl_xor(lpb, 32);
    float inva = 1.f / lpa, invb = 1.f / lpb;
    int b = bh >> 2, head = bh & 3;
    size_t rowa = (size_t)b * 1024 + qb * 128 + wid * 32 + lm;
    unsigned short* da = o_t + rowa * 512 + head * 128;
    unsigned short* db = da + (size_t)16 * 512;
#pragma unroll
    for (int t8 = 0; t8 < 8; ++t8) {
        uint2 pr;
        pr.x = cvtpk(oa[t8][0] * inva, oa[t8][1] * inva);
        pr.y = cvtpk(oa[t8][2] * inva, oa[t8][3] * inva);
        *(uint2*)&da[t8 * 16 + q4 * 4] = pr;
        pr.x = cvtpk(ob[t8][0] * invb, ob[t8][1] * invb);
        pr.y = cvtpk(ob[t8][2] * invb, ob[t8][3] * invb);
        *(uint2*)&db[t8 * 16 + q4 * 4] = pr;
    }
}

extern "C" void kernel_launch(void* const* d_in, const int* in_sizes, int n_in,
                              void* d_out, int out_size, void* d_ws, size_t ws_size,
                              hipStream_t stream) {
    const float* x = (const float*)d_in[0];
    const float* gnw = (const float*)d_in[1];
    const float* gnb = (const float*)d_in[2];
    const float* qkvw = (const float*)d_in[3];
    const float* qkvb = (const float*)d_in[4];
    const float* projw = (const float*)d_in[5];
    const float* projb = (const float*)d_in[6];
    float* out = (float*)d_out;
    char* ws = (char*)d_ws;

    unsigned short* wq = (unsigned short*)(ws);                  // 1536x512 bf16
    unsigned short* wp = (unsigned short*)(ws + 1572864);        // 512x512 bf16
    float* stats = (float*)(ws + 2097152);                       // 512 x {mean,rstd}
    unsigned short* ht = (unsigned short*)(ws + 2101248);        // h_t [16384][512] bf16
    unsigned short* Qb = (unsigned short*)(ws + 18878464);       // [64][1024][128] (pre-scaled)
    unsigned short* Kb = (unsigned short*)(ws + 35655680);       // [64][1024][128]
    unsigned short* Vb = (unsigned short*)(ws + 52432896);       // [64][128][1024] (m-permuted)
    unsigned short* ot = ht;                                     // reuse h_t region

    k_wconv<<<dim3(4096), dim3(256), 0, stream>>>(qkvw, projw, wq);
    k_gnstats<<<dim3(512), dim3(256), 0, stream>>>(x, stats);
    k_gnapply<<<dim3(512), dim3(256), 0, stream>>>(x, gnw, gnb, stats, ht);
    k_gemm<<<dim3(12, 128), dim3(256), 0, stream>>>(wq, ht, qkvb, 0, Qb, Kb, Vb, nullptr, nullptr);
    k_attn<<<dim3(8, 64), dim3(256), 0, stream>>>(Qb, Kb, Vb, ot);
    k_gemm<<<dim3(4, 128), dim3(256), 0, stream>>>(wp, ot, projb, 1, nullptr, nullptr, nullptr, x, out);
}

// Round 4
// 131.412 us; speedup vs baseline: 1.7319x; 1.1285x over previous
//
#include <hip/hip_runtime.h>

typedef __attribute__((ext_vector_type(4))) float f32x4;
typedef __attribute__((ext_vector_type(8))) short s16x8;

#define MFMA16(a, b, c) __builtin_amdgcn_mfma_f32_16x16x32_bf16((a), (b), (c), 0, 0, 0)

__device__ __forceinline__ unsigned short f2bf(float f) {
    union { float f; unsigned u; } v; v.f = f;
    unsigned u = v.u + 0x7FFFu + ((v.u >> 16) & 1u);
    return (unsigned short)(u >> 16);
}

__device__ __forceinline__ unsigned cvtpk(float lo, float hi) {
    unsigned r;
    asm("v_cvt_pk_bf16_f32 %0, %1, %2" : "=v"(r) : "v"(lo), "v"(hi));
    return r;
}

__device__ __forceinline__ float exp2f_fast(float x) {
    float r;
    asm("v_exp_f32 %0, %1" : "=v"(r) : "v"(x));
    return r;
}

__device__ __forceinline__ void gll16(const unsigned short* g, unsigned short* l) {
    __builtin_amdgcn_global_load_lds((const __attribute__((address_space(1))) void*)g,
                                     (__attribute__((address_space(3))) void*)l, 16, 0, 0);
}

// ---------------- kernel 1: convert qkv_w / proj_w fp32 -> bf16 ----------------
__global__ __launch_bounds__(256) void k_wconv(const float* __restrict__ qkv_w,
                                               const float* __restrict__ proj_w,
                                               unsigned short* __restrict__ wout) {
    int i = blockIdx.x * 256 + threadIdx.x;
    const int NQ = 3 * 512 * 512;
    float v = (i < NQ) ? qkv_w[i] : proj_w[i - NQ];
    wout[i] = f2bf(v);
}

// ---------------- kernel 2: group-norm stats (mean, rstd) per (b,g) ----------------
__global__ __launch_bounds__(256) void k_gnstats(const float* __restrict__ x,
                                                 float* __restrict__ stats) {
    int bg = blockIdx.x; // 0..511, group block is 16*1024 contiguous floats
    const float4* p = (const float4*)(x + (size_t)bg * 16384);
    float s = 0.f, ss = 0.f;
    for (int i = threadIdx.x; i < 4096; i += 256) {
        float4 v = p[i];
        s += v.x + v.y + v.z + v.w;
        ss += v.x * v.x + v.y * v.y + v.z * v.z + v.w * v.w;
    }
    for (int w = 1; w < 64; w <<= 1) { s += __shfl_xor(s, w); ss += __shfl_xor(ss, w); }
    __shared__ float rs[4], rss[4];
    int wid = threadIdx.x >> 6;
    if ((threadIdx.x & 63) == 0) { rs[wid] = s; rss[wid] = ss; }
    __syncthreads();
    if (threadIdx.x == 0) {
        float S = rs[0] + rs[1] + rs[2] + rs[3];
        float SS = rss[0] + rss[1] + rss[2] + rss[3];
        float mean = S * (1.f / 16384.f);
        float var = SS * (1.f / 16384.f) - mean * mean;
        stats[bg * 2] = mean;
        stats[bg * 2 + 1] = rsqrtf(var + 1e-5f);
    }
}

// ---------------- kernel 3: GN apply + transpose -> h_t[bn][c] bf16 ----------------
__global__ __launch_bounds__(256) void k_gnapply(const float* __restrict__ x,
                                                 const float* __restrict__ gnw,
                                                 const float* __restrict__ gnb,
                                                 const float* __restrict__ stats,
                                                 unsigned short* __restrict__ h_t) {
    int b = blockIdx.x >> 5, nb = blockIdx.x & 31;
    int n0 = nb * 32;
    __shared__ unsigned short lds[32][520];
    int t = threadIdx.x;
    int f4 = t & 7, c0 = t >> 3;
    for (int c = c0; c < 512; c += 32) {
        int g = c >> 4;
        float mean = stats[(b * 32 + g) * 2], rstd = stats[(b * 32 + g) * 2 + 1];
        float sc = gnw[c] * rstd;
        float sh = gnb[c] - mean * sc;
        float4 v = *(const float4*)(x + ((size_t)(b * 512 + c)) * 1024 + n0 + f4 * 4);
        lds[f4 * 4 + 0][c] = f2bf(v.x * sc + sh);
        lds[f4 * 4 + 1][c] = f2bf(v.y * sc + sh);
        lds[f4 * 4 + 2][c] = f2bf(v.z * sc + sh);
        lds[f4 * 4 + 3][c] = f2bf(v.w * sc + sh);
    }
    __syncthreads();
    int ch = t & 63;
    for (int nl = t >> 6; nl < 32; nl += 4) {
        *(uint4*)(h_t + ((size_t)(b * 1024 + n0 + nl)) * 512 + ch * 8) =
            *(const uint4*)(&lds[nl][ch * 8]);
    }
}

// ---------------- kernel 4/6: BT-GEMM, 128x128 tile, K=512 ----------------
// C[m][n] = sum_k A[m][k] * Bt[n][k]  (both bf16 row-major, K=512)
// 1D grid, XCD-affinity swizzle: all blocks sharing a B-tile -> same XCD.
// mode 0: scatter to Q[bh][n][d] (pre-scaled by 1/sqrt(d)*log2e), K[bh][m][d],
//         V[bh][d][m-permuted]
// mode 1: out[b][oc][n] = x[...] + bias[oc] + C   (fp32)
__global__ __launch_bounds__(256) void k_gemm(const unsigned short* __restrict__ A,
                                              const unsigned short* __restrict__ Bt,
                                              const float* __restrict__ bias, int mode,
                                              unsigned short* __restrict__ Qo,
                                              unsigned short* __restrict__ Ko,
                                              unsigned short* __restrict__ Vo,
                                              const float* __restrict__ xres,
                                              float* __restrict__ out) {
    const int Kd = 512;
    int id = blockIdx.x;
    int xcd = id & 7, j = id >> 3;
    int nt = xcd + 8 * (j & 15);   // B-tile: 16 per XCD, L2-resident (2.1 MB)
    int mt = j >> 4;               // A sweeps within XCD
    int t = threadIdx.x, wid = t >> 6, lane = t & 63;
    int lm = lane & 15, q4 = lane >> 4;
    int wm = wid >> 1, wn = wid & 1;
    __shared__ unsigned short ldsA[2][4096];
    __shared__ unsigned short ldsB[2][4096];
    int m0 = mt * 128, n0 = nt * 128;

    // hoisted staging pointers (chunk-XOR swizzle folded into global src)
    const unsigned short* gA[2];
    const unsigned short* gB[2];
    unsigned short* dA[2][2];
    unsigned short* dB[2][2];
#pragma unroll
    for (int h = 0; h < 2; ++h) {
        int cib = h * 256 + wid * 64;
        int ci = cib + lane;
        int r = ci >> 2;
        int cc = (ci & 3) ^ (r & 3);
        gA[h] = A + (size_t)(m0 + r) * Kd + cc * 8;
        gB[h] = Bt + (size_t)(n0 + r) * Kd + cc * 8;
        dA[0][h] = &ldsA[0][cib * 8];
        dA[1][h] = &ldsA[1][cib * 8];
        dB[0][h] = &ldsB[0][cib * 8];
        dB[1][h] = &ldsB[1][cib * 8];
    }

    f32x4 z = {0.f, 0.f, 0.f, 0.f};
    f32x4 acc[4][4];
#pragma unroll
    for (int fi = 0; fi < 4; ++fi)
#pragma unroll
        for (int fj = 0; fj < 4; ++fj) acc[fi][fj] = z;

    // prologue stage k=0 into buf0
    gll16(gA[0], dA[0][0]); gll16(gB[0], dB[0][0]);
    gll16(gA[1], dA[0][1]); gll16(gB[1], dB[0][1]);
    gA[0] += 32; gA[1] += 32; gB[0] += 32; gB[1] += 32;

    const int NK = 16;
    for (int ks = 0; ks < NK; ++ks) {
        int cur = ks & 1;
        if (ks + 1 < NK) {
            int nb = cur ^ 1;
            gll16(gA[0], dA[nb][0]); gll16(gB[0], dB[nb][0]);
            gll16(gA[1], dA[nb][1]); gll16(gB[1], dB[nb][1]);
            gA[0] += 32; gA[1] += 32; gB[0] += 32; gB[1] += 32;
            asm volatile("s_waitcnt vmcnt(4)" ::: "memory");
        } else {
            asm volatile("s_waitcnt vmcnt(0)" ::: "memory");
        }
        __builtin_amdgcn_s_barrier();
        asm volatile("" ::: "memory");
        const unsigned short* lA = ldsA[cur];
        const unsigned short* lB = ldsB[cur];
        s16x8 af[4], bg[4];
#pragma unroll
        for (int fi = 0; fi < 4; ++fi) {
            int rA = wm * 64 + fi * 16 + lm;
            af[fi] = *(const s16x8*)&lA[(rA * 4 + (q4 ^ (lm & 3))) * 8];
        }
#pragma unroll
        for (int fj = 0; fj < 4; ++fj) {
            int rB = wn * 64 + fj * 16 + lm;
            bg[fj] = *(const s16x8*)&lB[(rB * 4 + (q4 ^ (lm & 3))) * 8];
        }
#pragma unroll
        for (int fi = 0; fi < 4; ++fi)
#pragma unroll
            for (int fj = 0; fj < 4; ++fj) acc[fi][fj] = MFMA16(af[fi], bg[fj], acc[fi][fj]);
        asm volatile("" ::: "memory");
        __builtin_amdgcn_s_barrier();
    }

    if (mode == 0) {
        int part = mt >> 2;  // 0=Q 1=K 2=V (M-tile never straddles parts)
        int head = mt & 3;
        int b = nt >> 3;
        int bh = b * 4 + head;
        const float qscale = 0.08838834764831845f * 1.4426950408889634f;  // 1/sqrt(128)*log2e
#pragma unroll
        for (int fi = 0; fi < 4; ++fi) {
            int ddb = wm * 64 + fi * 16 + 4 * q4;  // + i -> d within head
            float bv[4];
#pragma unroll
            for (int i = 0; i < 4; ++i) bv[i] = bias[mt * 128 + ddb + i];
#pragma unroll
            for (int fj = 0; fj < 4; ++fj) {
                int n = ((nt & 7) << 7) + wn * 64 + fj * 16 + lm;
                f32x4 v = acc[fi][fj];
                if (part == 0) {
                    uint2 pr;
                    pr.x = cvtpk((v[0] + bv[0]) * qscale, (v[1] + bv[1]) * qscale);
                    pr.y = cvtpk((v[2] + bv[2]) * qscale, (v[3] + bv[3]) * qscale);
                    *(uint2*)(Qo + ((size_t)bh * 1024 + n) * 128 + ddb) = pr;
                } else if (part == 1) {
                    uint2 pr;
                    pr.x = cvtpk(v[0] + bv[0], v[1] + bv[1]);
                    pr.y = cvtpk(v[2] + bv[2], v[3] + bv[3]);
                    *(uint2*)(Ko + ((size_t)bh * 1024 + n) * 128 + ddb) = pr;
                } else {
                    // permute m within each 32-block so attn's PV A-frag k-order
                    // matches the lane-local P register order (perm(8a+j))
                    int r = (fj & 1) * 16 + lm;
                    int kidx = (lm >> 2) * 8 + (fj & 1) * 4 + (lm & 3);
                    int np = n - r + kidx;
#pragma unroll
                    for (int i = 0; i < 4; ++i)
                        Vo[((size_t)bh * 128 + ddb + i) * 1024 + np] = f2bf(v[i] + bv[i]);
                }
            }
        }
    } else {
        int b = nt >> 3;
#pragma unroll
        for (int fi = 0; fi < 4; ++fi) {
            int ocb = m0 + wm * 64 + fi * 16 + 4 * q4;
            float bv[4];
#pragma unroll
            for (int i = 0; i < 4; ++i) bv[i] = bias[ocb + i];
#pragma unroll
            for (int fj = 0; fj < 4; ++fj) {
                int n = ((nt & 7) << 7) + wn * 64 + fj * 16 + lm;
#pragma unroll
                for (int i = 0; i < 4; ++i) {
                    size_t idx = ((size_t)b * 512 + ocb + i) * 1024 + n;
                    out[idx] = xres[idx] + bv[i] + acc[fi][fj][i];
                }
            }
        }
    }
}

// ---------------- kernel 5: flash attention, 32 queries/wave ----------------
// S^T = mfma(K,Q): lane owns P[8 m-slots][query lm] (+ query 16+lm) in regs.
// exp2 domain (log2e folded into Q). Deferred l-sum (one reduce at end).
// Defer-max on LOCAL max via __all. V stored m-permuted feeds PV directly.
__global__ __launch_bounds__(256, 2) void k_attn(const unsigned short* __restrict__ Q,
                                                 const unsigned short* __restrict__ K,
                                                 const unsigned short* __restrict__ V,
                                                 unsigned short* __restrict__ o_t) {
    int id = blockIdx.y * 8 + blockIdx.x;
    int bh = (id & 7) + ((id >> 6) << 3);   // XCD swizzle: all 8 q-blocks of a bh
    int qb = (id >> 3) & 7;                 // land on one XCD for K/V L2 reuse
    int t = threadIdx.x, wid = t >> 6, lane = t & 63;
    int lm = lane & 15, q4 = lane >> 4;
    __shared__ unsigned short ldsK[2][4096];  // [m=32][d=128], chunk^(m&7) swizzle
    __shared__ unsigned short ldsV[2][4096];  // [d=128][k=32], chunk^((d>>1)&3) swizzle
    const unsigned short* Qg = Q + ((size_t)bh * 1024 + qb * 128 + wid * 32) * 128;
    const unsigned short* Kg = K + (size_t)bh * 1024 * 128;
    const unsigned short* Vg = V + (size_t)bh * 128 * 1024;

    s16x8 qf0[4], qf1[4];
#pragma unroll
    for (int dc = 0; dc < 4; ++dc) {
        qf0[dc] = *(const s16x8*)&Qg[lm * 128 + dc * 32 + q4 * 8];
        qf1[dc] = *(const s16x8*)&Qg[(16 + lm) * 128 + dc * 32 + q4 * 8];
    }

    // hoisted staging pointers (strength-reduced per-iter increments)
    const unsigned short* gk[2];
    const unsigned short* gv[2];
    unsigned short* lkd[2][2];
    unsigned short* lvd[2][2];
#pragma unroll
    for (int h = 0; h < 2; ++h) {
        int cib = h * 256 + wid * 64;
        int ci = cib + lane;
        int mr = ci >> 4, cl = ci & 15;
        gk[h] = Kg + mr * 128 + (cl ^ (mr & 7)) * 8;
        int d = ci >> 2, kc = ci & 3;
        gv[h] = Vg + (size_t)d * 1024 + (kc ^ ((d >> 1) & 3)) * 8;
        lkd[0][h] = &ldsK[0][cib * 8];
        lkd[1][h] = &ldsK[1][cib * 8];
        lvd[0][h] = &ldsV[0][cib * 8];
        lvd[1][h] = &ldsV[1][cib * 8];
    }
    gll16(gk[0], lkd[0][0]); gll16(gk[1], lkd[0][1]);
    gll16(gv[0], lvd[0][0]); gll16(gv[1], lvd[0][1]);
    gk[0] += 4096; gk[1] += 4096; gv[0] += 32; gv[1] += 32;

    f32x4 z = {0.f, 0.f, 0.f, 0.f};
    f32x4 oa[8], ob[8];
#pragma unroll
    for (int i = 0; i < 8; ++i) { oa[i] = z; ob[i] = z; }
    float mra = -1e30f, mrb = -1e30f, lpa = 0.f, lpb = 0.f;

    for (int ms = 0; ms < 32; ++ms) {
        int cur = ms & 1;
        if (ms < 31) {
            int nb = cur ^ 1;
            gll16(gk[0], lkd[nb][0]); gll16(gk[1], lkd[nb][1]);
            gll16(gv[0], lvd[nb][0]); gll16(gv[1], lvd[nb][1]);
            gk[0] += 4096; gk[1] += 4096; gv[0] += 32; gv[1] += 32;
            asm volatile("s_waitcnt vmcnt(4)" ::: "memory");
        } else {
            asm volatile("s_waitcnt vmcnt(0)" ::: "memory");
        }
        __builtin_amdgcn_s_barrier();
        const unsigned short* lK = ldsK[cur];
        const unsigned short* lV = ldsV[cur];

        f32x4 s0a = z, s0b = z, s1a = z, s1b = z;
        __builtin_amdgcn_s_setprio(1);
#pragma unroll
        for (int dc = 0; dc < 4; ++dc) {
            int sw = ((dc * 4 + q4) ^ (lm & 7)) * 8;
            s16x8 k0 = *(const s16x8*)&lK[lm * 128 + sw];
            s16x8 k1 = *(const s16x8*)&lK[(16 + lm) * 128 + sw];
            s0a = MFMA16(k0, qf0[dc], s0a);
            s0b = MFMA16(k0, qf1[dc], s0b);
            s1a = MFMA16(k1, qf0[dc], s1a);
            s1b = MFMA16(k1, qf1[dc], s1b);
        }
        __builtin_amdgcn_s_setprio(0);

        float tma = fmaxf(fmaxf(fmaxf(s0a[0], s0a[1]), fmaxf(s0a[2], s0a[3])),
                          fmaxf(fmaxf(s1a[0], s1a[1]), fmaxf(s1a[2], s1a[3])));
        float tmb = fmaxf(fmaxf(fmaxf(s0b[0], s0b[1]), fmaxf(s0b[2], s0b[3])),
                          fmaxf(fmaxf(s1b[0], s1b[1]), fmaxf(s1b[2], s1b[3])));
        if (!__all(tma <= mra + 8.f && tmb <= mrb + 8.f)) {  // defer-max (T13)
            tma = fmaxf(tma, __shfl_xor(tma, 16));
            tma = fmaxf(tma, __shfl_xor(tma, 32));
            tmb = fmaxf(tmb, __shfl_xor(tmb, 16));
            tmb = fmaxf(tmb, __shfl_xor(tmb, 32));
            float mna = fmaxf(mra, tma), mnb = fmaxf(mrb, tmb);
            float ca = exp2f_fast(mra - mna), cb = exp2f_fast(mrb - mnb);
            lpa *= ca; lpb *= cb;
#pragma unroll
            for (int t8 = 0; t8 < 8; ++t8)
#pragma unroll
                for (int i = 0; i < 4; ++i) { oa[t8][i] *= ca; ob[t8][i] *= cb; }
            mra = mna; mrb = mnb;
        }
        float pa[8], pb[8];
#pragma unroll
        for (int i = 0; i < 4; ++i) {
            pa[i]     = exp2f_fast(s0a[i] - mra);
            pa[4 + i] = exp2f_fast(s1a[i] - mra);
            pb[i]     = exp2f_fast(s0b[i] - mrb);
            pb[4 + i] = exp2f_fast(s1b[i] - mrb);
        }
#pragma unroll
        for (int i = 0; i < 8; ++i) { lpa += pa[i]; lpb += pb[i]; }
        union { s16x8 v; unsigned u[4]; } fa, fb;
        fa.u[0] = cvtpk(pa[0], pa[1]); fa.u[1] = cvtpk(pa[2], pa[3]);
        fa.u[2] = cvtpk(pa[4], pa[5]); fa.u[3] = cvtpk(pa[6], pa[7]);
        fb.u[0] = cvtpk(pb[0], pb[1]); fb.u[1] = cvtpk(pb[2], pb[3]);
        fb.u[2] = cvtpk(pb[4], pb[5]); fb.u[3] = cvtpk(pb[6], pb[7]);

        __builtin_amdgcn_s_setprio(1);
#pragma unroll
        for (int t8 = 0; t8 < 8; ++t8) {
            int r = t8 * 16 + lm;
            s16x8 vf = *(const s16x8*)&lV[r * 32 + ((q4 ^ ((lm >> 1) & 3)) * 8)];
            oa[t8] = MFMA16(vf, fa.v, oa[t8]);
            ob[t8] = MFMA16(vf, fb.v, ob[t8]);
        }
        __builtin_amdgcn_s_setprio(0);
        __builtin_amdgcn_s_barrier();
    }

    lpa += __shfl_xor(lpa, 16); lpa += __shfl_xor(lpa, 32);
    lpb += __shfl_xor(lpb, 16); lpb += __shfl_xor(lpb, 32);
    float inva = 1.f / lpa, invb = 1.f / lpb;
    int b = bh >> 2, head = bh & 3;
    size_t rowa = (size_t)b * 1024 + qb * 128 + wid * 32 + lm;
    unsigned short* da = o_t + rowa * 512 + head * 128;
    unsigned short* db = da + (size_t)16 * 512;
#pragma unroll
    for (int t8 = 0; t8 < 8; ++t8) {
        uint2 pr;
        pr.x = cvtpk(oa[t8][0] * inva, oa[t8][1] * inva);
        pr.y = cvtpk(oa[t8][2] * inva, oa[t8][3] * inva);
        *(uint2*)&da[t8 * 16 + q4 * 4] = pr;
        pr.x = cvtpk(ob[t8][0] * invb, ob[t8][1] * invb);
        pr.y = cvtpk(ob[t8][2] * invb, ob[t8][3] * invb);
        *(uint2*)&db[t8 * 16 + q4 * 4] = pr;
    }
}

extern "C" void kernel_launch(void* const* d_in, const int* in_sizes, int n_in,
                              void* d_out, int out_size, void* d_ws, size_t ws_size,
                              hipStream_t stream) {
    const float* x = (const float*)d_in[0];
    const float* gnw = (const float*)d_in[1];
    const float* gnb = (const float*)d_in[2];
    const float* qkvw = (const float*)d_in[3];
    const float* qkvb = (const float*)d_in[4];
    const float* projw = (const float*)d_in[5];
    const float* projb = (const float*)d_in[6];
    float* out = (float*)d_out;
    char* ws = (char*)d_ws;

    unsigned short* wq = (unsigned short*)(ws);                  // 1536x512 bf16
    unsigned short* wp = (unsigned short*)(ws + 1572864);        // 512x512 bf16
    float* stats = (float*)(ws + 2097152);                       // 512 x {mean,rstd}
    unsigned short* ht = (unsigned short*)(ws + 2101248);        // h_t [16384][512] bf16
    unsigned short* Qb = (unsigned short*)(ws + 18878464);       // [64][1024][128] (pre-scaled)
    unsigned short* Kb = (unsigned short*)(ws + 35655680);       // [64][1024][128]
    unsigned short* Vb = (unsigned short*)(ws + 52432896);       // [64][128][1024] (m-permuted)
    unsigned short* ot = ht;                                     // reuse h_t region

    k_wconv<<<dim3(4096), dim3(256), 0, stream>>>(qkvw, projw, wq);
    k_gnstats<<<dim3(512), dim3(256), 0, stream>>>(x, stats);
    k_gnapply<<<dim3(512), dim3(256), 0, stream>>>(x, gnw, gnb, stats, ht);
    k_gemm<<<dim3(1536), dim3(256), 0, stream>>>(wq, ht, qkvb, 0, Qb, Kb, Vb, nullptr, nullptr);
    k_attn<<<dim3(8, 64), dim3(256), 0, stream>>>(Qb, Kb, Vb, ot);
    k_gemm<<<dim3(512), dim3(256), 0, stream>>>(wp, ot, projb, 1, nullptr, nullptr, nullptr, x, out);
}

// Round 5
// 128.531 us; speedup vs baseline: 1.7707x; 1.0224x over previous
//
#include <hip/hip_runtime.h>

typedef __attribute__((ext_vector_type(4))) float f32x4;
typedef __attribute__((ext_vector_type(8))) short s16x8;

#define MFMA16(a, b, c) __builtin_amdgcn_mfma_f32_16x16x32_bf16((a), (b), (c), 0, 0, 0)

__device__ __forceinline__ unsigned short f2bf(float f) {
    union { float f; unsigned u; } v; v.f = f;
    unsigned u = v.u + 0x7FFFu + ((v.u >> 16) & 1u);
    return (unsigned short)(u >> 16);
}

__device__ __forceinline__ unsigned cvtpk(float lo, float hi) {
    unsigned r;
    asm("v_cvt_pk_bf16_f32 %0, %1, %2" : "=v"(r) : "v"(lo), "v"(hi));
    return r;
}

__device__ __forceinline__ float exp2f_fast(float x) {
    float r;
    asm("v_exp_f32 %0, %1" : "=v"(r) : "v"(x));
    return r;
}

__device__ __forceinline__ void gll16(const unsigned short* g, unsigned short* l) {
    __builtin_amdgcn_global_load_lds((const __attribute__((address_space(1))) void*)g,
                                     (__attribute__((address_space(3))) void*)l, 16, 0, 0);
}

// ---------------- kernel 1: convert qkv_w / proj_w fp32 -> bf16 ----------------
__global__ __launch_bounds__(256) void k_wconv(const float* __restrict__ qkv_w,
                                               const float* __restrict__ proj_w,
                                               unsigned short* __restrict__ wout) {
    int i = blockIdx.x * 256 + threadIdx.x;
    const int NQ = 3 * 512 * 512;
    float v = (i < NQ) ? qkv_w[i] : proj_w[i - NQ];
    wout[i] = f2bf(v);
}

// ------- kernel 2: fused group-norm (stats + apply + transpose) per (b,g) -------
// block = one (b,g): 16 channels x 1024 pixels = 64KB fp32. Pass 1 computes
// mean/rstd (second read is L2-hot), pass 2 normalizes into padded LDS and
// writes h_t[bn][c] bf16 with bulk uint4 stores.
__global__ __launch_bounds__(256) void k_gn(const float* __restrict__ x,
                                            const float* __restrict__ gnw,
                                            const float* __restrict__ gnb,
                                            unsigned short* __restrict__ h_t) {
    int bg = blockIdx.x;
    int b = bg >> 5, g = bg & 31;
    int t = threadIdx.x;
    const float4* p = (const float4*)(x + (size_t)bg * 16384);
    float s = 0.f, ss = 0.f;
    for (int i = t; i < 4096; i += 256) {
        float4 v = p[i];
        s += v.x + v.y + v.z + v.w;
        ss += v.x * v.x + v.y * v.y + v.z * v.z + v.w * v.w;
    }
    for (int w = 1; w < 64; w <<= 1) { s += __shfl_xor(s, w); ss += __shfl_xor(ss, w); }
    __shared__ float rs[4], rss[4], mv[2];
    __shared__ unsigned short ldt[1024][18];  // padded: stride 36B kills conflicts
    int wid = t >> 6;
    if ((t & 63) == 0) { rs[wid] = s; rss[wid] = ss; }
    __syncthreads();
    if (t == 0) {
        float S = rs[0] + rs[1] + rs[2] + rs[3];
        float SS = rss[0] + rss[1] + rss[2] + rss[3];
        float mean = S * (1.f / 16384.f);
        float var = SS * (1.f / 16384.f) - mean * mean;
        mv[0] = mean; mv[1] = rsqrtf(var + 1e-5f);
    }
    __syncthreads();
    int c = t >> 4, f4 = t & 15;
    float mean = mv[0], rstd = mv[1];
    float sc = gnw[g * 16 + c] * rstd;
    float sh = gnb[g * 16 + c] - mean * sc;
    const float4* pc = (const float4*)(x + ((size_t)(b * 512 + g * 16 + c)) * 1024);
#pragma unroll
    for (int i = 0; i < 16; ++i) {
        int n = i * 64 + f4 * 4;
        float4 v = pc[n >> 2];
        ldt[n + 0][c] = f2bf(v.x * sc + sh);
        ldt[n + 1][c] = f2bf(v.y * sc + sh);
        ldt[n + 2][c] = f2bf(v.z * sc + sh);
        ldt[n + 3][c] = f2bf(v.w * sc + sh);
    }
    __syncthreads();
    int half = t & 1;
#pragma unroll
    for (int i = 0; i < 8; ++i) {
        int row = i * 128 + (t >> 1);
        *(uint4*)(h_t + ((size_t)(b * 1024 + row)) * 512 + g * 16 + half * 8) =
            *(const uint4*)(&ldt[row][half * 8]);
    }
}

// ---------------- kernel 4/6: BT-GEMM, 128x128 tile, K=512 ----------------
// C[m][n] = sum_k A[m][k] * Bt[n][k]  (both bf16 row-major, K=512)
// 1D grid, XCD-affinity swizzle: all blocks sharing a B-tile -> same XCD.
// mode 0: scatter to Q[bh][n][d] (pre-scaled by 1/sqrt(d)*log2e), K[bh][m][d],
//         V[bh][d][m-permuted]
// mode 1: out[b][oc][n] = x[...] + bias[oc] + C   (fp32)
__global__ __launch_bounds__(256) void k_gemm(const unsigned short* __restrict__ A,
                                              const unsigned short* __restrict__ Bt,
                                              const float* __restrict__ bias, int mode,
                                              unsigned short* __restrict__ Qo,
                                              unsigned short* __restrict__ Ko,
                                              unsigned short* __restrict__ Vo,
                                              const float* __restrict__ xres,
                                              float* __restrict__ out) {
    const int Kd = 512;
    int id = blockIdx.x;
    int xcd = id & 7, j = id >> 3;
    int nt = xcd + 8 * (j & 15);   // B-tile: 16 per XCD, L2-resident (2.1 MB)
    int mt = j >> 4;               // A sweeps within XCD
    int t = threadIdx.x, wid = t >> 6, lane = t & 63;
    int lm = lane & 15, q4 = lane >> 4;
    int wm = wid >> 1, wn = wid & 1;
    __shared__ unsigned short ldsA[2][4096];
    __shared__ unsigned short ldsB[2][4096];
    int m0 = mt * 128, n0 = nt * 128;

    // hoisted staging pointers (chunk-XOR swizzle folded into global src)
    const unsigned short* gA[2];
    const unsigned short* gB[2];
    unsigned short* dA[2][2];
    unsigned short* dB[2][2];
#pragma unroll
    for (int h = 0; h < 2; ++h) {
        int cib = h * 256 + wid * 64;
        int ci = cib + lane;
        int r = ci >> 2;
        int cc = (ci & 3) ^ (r & 3);
        gA[h] = A + (size_t)(m0 + r) * Kd + cc * 8;
        gB[h] = Bt + (size_t)(n0 + r) * Kd + cc * 8;
        dA[0][h] = &ldsA[0][cib * 8];
        dA[1][h] = &ldsA[1][cib * 8];
        dB[0][h] = &ldsB[0][cib * 8];
        dB[1][h] = &ldsB[1][cib * 8];
    }

    f32x4 z = {0.f, 0.f, 0.f, 0.f};
    f32x4 acc[4][4];
#pragma unroll
    for (int fi = 0; fi < 4; ++fi)
#pragma unroll
        for (int fj = 0; fj < 4; ++fj) acc[fi][fj] = z;

    // prologue stage k=0 into buf0
    gll16(gA[0], dA[0][0]); gll16(gB[0], dB[0][0]);
    gll16(gA[1], dA[0][1]); gll16(gB[1], dB[0][1]);
    gA[0] += 32; gA[1] += 32; gB[0] += 32; gB[1] += 32;

    const int NK = 16;
    for (int ks = 0; ks < NK; ++ks) {
        int cur = ks & 1;
        if (ks + 1 < NK) {
            int nb = cur ^ 1;
            gll16(gA[0], dA[nb][0]); gll16(gB[0], dB[nb][0]);
            gll16(gA[1], dA[nb][1]); gll16(gB[1], dB[nb][1]);
            gA[0] += 32; gA[1] += 32; gB[0] += 32; gB[1] += 32;
            asm volatile("s_waitcnt vmcnt(4)" ::: "memory");
        } else {
            asm volatile("s_waitcnt vmcnt(0)" ::: "memory");
        }
        __builtin_amdgcn_s_barrier();
        asm volatile("" ::: "memory");
        const unsigned short* lA = ldsA[cur];
        const unsigned short* lB = ldsB[cur];
        s16x8 af[4], bg[4];
#pragma unroll
        for (int fi = 0; fi < 4; ++fi) {
            int rA = wm * 64 + fi * 16 + lm;
            af[fi] = *(const s16x8*)&lA[(rA * 4 + (q4 ^ (lm & 3))) * 8];
        }
#pragma unroll
        for (int fj = 0; fj < 4; ++fj) {
            int rB = wn * 64 + fj * 16 + lm;
            bg[fj] = *(const s16x8*)&lB[(rB * 4 + (q4 ^ (lm & 3))) * 8];
        }
#pragma unroll
        for (int fi = 0; fi < 4; ++fi)
#pragma unroll
            for (int fj = 0; fj < 4; ++fj) acc[fi][fj] = MFMA16(af[fi], bg[fj], acc[fi][fj]);
        asm volatile("" ::: "memory");
        __builtin_amdgcn_s_barrier();
    }

    if (mode == 0) {
        int part = mt >> 2;  // 0=Q 1=K 2=V (M-tile never straddles parts)
        int head = mt & 3;
        int b = nt >> 3;
        int bh = b * 4 + head;
        const float qscale = 0.08838834764831845f * 1.4426950408889634f;  // 1/sqrt(128)*log2e
#pragma unroll
        for (int fi = 0; fi < 4; ++fi) {
            int ddb = wm * 64 + fi * 16 + 4 * q4;  // + i -> d within head
            float bv[4];
#pragma unroll
            for (int i = 0; i < 4; ++i) bv[i] = bias[mt * 128 + ddb + i];
#pragma unroll
            for (int fj = 0; fj < 4; ++fj) {
                int n = ((nt & 7) << 7) + wn * 64 + fj * 16 + lm;
                f32x4 v = acc[fi][fj];
                if (part == 0) {
                    uint2 pr;
                    pr.x = cvtpk((v[0] + bv[0]) * qscale, (v[1] + bv[1]) * qscale);
                    pr.y = cvtpk((v[2] + bv[2]) * qscale, (v[3] + bv[3]) * qscale);
                    *(uint2*)(Qo + ((size_t)bh * 1024 + n) * 128 + ddb) = pr;
                } else if (part == 1) {
                    uint2 pr;
                    pr.x = cvtpk(v[0] + bv[0], v[1] + bv[1]);
                    pr.y = cvtpk(v[2] + bv[2], v[3] + bv[3]);
                    *(uint2*)(Ko + ((size_t)bh * 1024 + n) * 128 + ddb) = pr;
                } else {
                    // permute m within each 32-block so attn's PV A-frag k-order
                    // matches the lane-local P register order (perm(8a+j))
                    int r = (fj & 1) * 16 + lm;
                    int kidx = (lm >> 2) * 8 + (fj & 1) * 4 + (lm & 3);
                    int np = n - r + kidx;
#pragma unroll
                    for (int i = 0; i < 4; ++i)
                        Vo[((size_t)bh * 128 + ddb + i) * 1024 + np] = f2bf(v[i] + bv[i]);
                }
            }
        }
    } else {
        int b = nt >> 3;
#pragma unroll
        for (int fi = 0; fi < 4; ++fi) {
            int ocb = m0 + wm * 64 + fi * 16 + 4 * q4;
            float bv[4];
#pragma unroll
            for (int i = 0; i < 4; ++i) bv[i] = bias[ocb + i];
#pragma unroll
            for (int fj = 0; fj < 4; ++fj) {
                int n = ((nt & 7) << 7) + wn * 64 + fj * 16 + lm;
#pragma unroll
                for (int i = 0; i < 4; ++i) {
                    size_t idx = ((size_t)b * 512 + ocb + i) * 1024 + n;
                    out[idx] = xres[idx] + bv[i] + acc[fi][fj][i];
                }
            }
        }
    }
}

// ---------------- kernel 5: flash attention, 32 q/wave, KVBLK=64 ----------------
// S^T = mfma(K,Q): lane owns P[8 m-slots][query lm] (+ query 16+lm) in regs.
// exp2 domain (log2e folded into Q). Two 32-key half-steps per barrier pair:
// h1's QK MFMA hides h0's softmax VALU. Staging: 8 gll16/tile, vmcnt(8).
__global__ __launch_bounds__(256, 2) void k_attn(const unsigned short* __restrict__ Q,
                                                 const unsigned short* __restrict__ K,
                                                 const unsigned short* __restrict__ V,
                                                 unsigned short* __restrict__ o_t) {
    int id = blockIdx.y * 8 + blockIdx.x;
    int bh = (id & 7) + ((id >> 6) << 3);   // XCD swizzle: all 8 q-blocks of a bh
    int qb = (id >> 3) & 7;                 // land on one XCD for K/V L2 reuse
    int t = threadIdx.x, wid = t >> 6, lane = t & 63;
    int lm = lane & 15, q4 = lane >> 4;
    __shared__ unsigned short ldsK[2][8192];  // [m=64][d=128], chunk^(m&7) swizzle
    __shared__ unsigned short ldsV[2][8192];  // [d=128][k=64], chunk^(d&7) swizzle
    const unsigned short* Qg = Q + ((size_t)bh * 1024 + qb * 128 + wid * 32) * 128;
    const unsigned short* Kg = K + (size_t)bh * 1024 * 128;
    const unsigned short* Vg = V + (size_t)bh * 128 * 1024;

    s16x8 qf0[4], qf1[4];
#pragma unroll
    for (int dc = 0; dc < 4; ++dc) {
        qf0[dc] = *(const s16x8*)&Qg[lm * 128 + dc * 32 + q4 * 8];
        qf1[dc] = *(const s16x8*)&Qg[(16 + lm) * 128 + dc * 32 + q4 * 8];
    }

    // hoisted staging pointers (strength-reduced per-iter increments)
    const unsigned short* gk[4];
    const unsigned short* gv[4];
    unsigned short* lkd[2][4];
    unsigned short* lvd[2][4];
#pragma unroll
    for (int h = 0; h < 4; ++h) {
        int cib = h * 256 + wid * 64;
        int ci = cib + lane;
        int mr = ci >> 4, cl = ci & 15;
        gk[h] = Kg + mr * 128 + (cl ^ (mr & 7)) * 8;
        int d = ci >> 3, kc = ci & 7;
        gv[h] = Vg + (size_t)d * 1024 + (kc ^ (d & 7)) * 8;
        lkd[0][h] = &ldsK[0][cib * 8];
        lkd[1][h] = &ldsK[1][cib * 8];
        lvd[0][h] = &ldsV[0][cib * 8];
        lvd[1][h] = &ldsV[1][cib * 8];
    }
#pragma unroll
    for (int h = 0; h < 4; ++h) { gll16(gk[h], lkd[0][h]); gll16(gv[h], lvd[0][h]); }
#pragma unroll
    for (int h = 0; h < 4; ++h) { gk[h] += 8192; gv[h] += 64; }

    f32x4 z = {0.f, 0.f, 0.f, 0.f};
    f32x4 oa[8], ob[8];
#pragma unroll
    for (int i = 0; i < 8; ++i) { oa[i] = z; ob[i] = z; }
    float mra = -1e30f, mrb = -1e30f, lpa = 0.f, lpb = 0.f;

    for (int ms = 0; ms < 16; ++ms) {
        int cur = ms & 1;
        if (ms < 15) {
            int nb = cur ^ 1;
#pragma unroll
            for (int h = 0; h < 4; ++h) { gll16(gk[h], lkd[nb][h]); gll16(gv[h], lvd[nb][h]); }
#pragma unroll
            for (int h = 0; h < 4; ++h) { gk[h] += 8192; gv[h] += 64; }
            asm volatile("s_waitcnt vmcnt(8)" ::: "memory");
        } else {
            asm volatile("s_waitcnt vmcnt(0)" ::: "memory");
        }
        __builtin_amdgcn_s_barrier();
        const unsigned short* lK = ldsK[cur];
        const unsigned short* lV = ldsV[cur];

#pragma unroll
        for (int hk = 0; hk < 2; ++hk) {
            f32x4 s0a = z, s0b = z, s1a = z, s1b = z;
            __builtin_amdgcn_s_setprio(1);
#pragma unroll
            for (int dc = 0; dc < 4; ++dc) {
                int sw = ((dc * 4 + q4) ^ (lm & 7)) * 8;
                s16x8 k0 = *(const s16x8*)&lK[(hk * 32 + lm) * 128 + sw];
                s16x8 k1 = *(const s16x8*)&lK[(hk * 32 + 16 + lm) * 128 + sw];
                s0a = MFMA16(k0, qf0[dc], s0a);
                s0b = MFMA16(k0, qf1[dc], s0b);
                s1a = MFMA16(k1, qf0[dc], s1a);
                s1b = MFMA16(k1, qf1[dc], s1b);
            }
            __builtin_amdgcn_s_setprio(0);

            float tma = fmaxf(fmaxf(fmaxf(s0a[0], s0a[1]), fmaxf(s0a[2], s0a[3])),
                              fmaxf(fmaxf(s1a[0], s1a[1]), fmaxf(s1a[2], s1a[3])));
            float tmb = fmaxf(fmaxf(fmaxf(s0b[0], s0b[1]), fmaxf(s0b[2], s0b[3])),
                              fmaxf(fmaxf(s1b[0], s1b[1]), fmaxf(s1b[2], s1b[3])));
            if (!__all(tma <= mra + 8.f && tmb <= mrb + 8.f)) {  // defer-max (T13)
                tma = fmaxf(tma, __shfl_xor(tma, 16));
                tma = fmaxf(tma, __shfl_xor(tma, 32));
                tmb = fmaxf(tmb, __shfl_xor(tmb, 16));
                tmb = fmaxf(tmb, __shfl_xor(tmb, 32));
                float mna = fmaxf(mra, tma), mnb = fmaxf(mrb, tmb);
                float ca = exp2f_fast(mra - mna), cb = exp2f_fast(mrb - mnb);
                lpa *= ca; lpb *= cb;
#pragma unroll
                for (int t8 = 0; t8 < 8; ++t8)
#pragma unroll
                    for (int i = 0; i < 4; ++i) { oa[t8][i] *= ca; ob[t8][i] *= cb; }
                mra = mna; mrb = mnb;
            }
            float pa[8], pb[8];
#pragma unroll
            for (int i = 0; i < 4; ++i) {
                pa[i]     = exp2f_fast(s0a[i] - mra);
                pa[4 + i] = exp2f_fast(s1a[i] - mra);
                pb[i]     = exp2f_fast(s0b[i] - mrb);
                pb[4 + i] = exp2f_fast(s1b[i] - mrb);
            }
#pragma unroll
            for (int i = 0; i < 8; ++i) { lpa += pa[i]; lpb += pb[i]; }
            union { s16x8 v; unsigned u[4]; } fa, fb;
            fa.u[0] = cvtpk(pa[0], pa[1]); fa.u[1] = cvtpk(pa[2], pa[3]);
            fa.u[2] = cvtpk(pa[4], pa[5]); fa.u[3] = cvtpk(pa[6], pa[7]);
            fb.u[0] = cvtpk(pb[0], pb[1]); fb.u[1] = cvtpk(pb[2], pb[3]);
            fb.u[2] = cvtpk(pb[4], pb[5]); fb.u[3] = cvtpk(pb[6], pb[7]);

            __builtin_amdgcn_s_setprio(1);
#pragma unroll
            for (int t8 = 0; t8 < 8; ++t8) {
                int r = t8 * 16 + lm;
                s16x8 vf = *(const s16x8*)&lV[r * 64 + (((hk * 4 + q4) ^ (lm & 7)) * 8)];
                oa[t8] = MFMA16(vf, fa.v, oa[t8]);
                ob[t8] = MFMA16(vf, fb.v, ob[t8]);
            }
            __builtin_amdgcn_s_setprio(0);
        }
        __builtin_amdgcn_s_barrier();
    }

    lpa += __shfl_xor(lpa, 16); lpa += __shfl_xor(lpa, 32);
    lpb += __shfl_xor(lpb, 16); lpb += __shfl_xor(lpb, 32);
    float inva = 1.f / lpa, invb = 1.f / lpb;
    int b = bh >> 2, head = bh & 3;
    size_t rowa = (size_t)b * 1024 + qb * 128 + wid * 32 + lm;
    unsigned short* da = o_t + rowa * 512 + head * 128;
    unsigned short* db = da + (size_t)16 * 512;
#pragma unroll
    for (int t8 = 0; t8 < 8; ++t8) {
        uint2 pr;
        pr.x = cvtpk(oa[t8][0] * inva, oa[t8][1] * inva);
        pr.y = cvtpk(oa[t8][2] * inva, oa[t8][3] * inva);
        *(uint2*)&da[t8 * 16 + q4 * 4] = pr;
        pr.x = cvtpk(ob[t8][0] * invb, ob[t8][1] * invb);
        pr.y = cvtpk(ob[t8][2] * invb, ob[t8][3] * invb);
        *(uint2*)&db[t8 * 16 + q4 * 4] = pr;
    }
}

extern "C" void kernel_launch(void* const* d_in, const int* in_sizes, int n_in,
                              void* d_out, int out_size, void* d_ws, size_t ws_size,
                              hipStream_t stream) {
    const float* x = (const float*)d_in[0];
    const float* gnw = (const float*)d_in[1];
    const float* gnb = (const float*)d_in[2];
    const float* qkvw = (const float*)d_in[3];
    const float* qkvb = (const float*)d_in[4];
    const float* projw = (const float*)d_in[5];
    const float* projb = (const float*)d_in[6];
    float* out = (float*)d_out;
    char* ws = (char*)d_ws;

    unsigned short* wq = (unsigned short*)(ws);                  // 1536x512 bf16
    unsigned short* wp = (unsigned short*)(ws + 1572864);        // 512x512 bf16
    unsigned short* ht = (unsigned short*)(ws + 2101248);        // h_t [16384][512] bf16
    unsigned short* Qb = (unsigned short*)(ws + 18878464);       // [64][1024][128] (pre-scaled)
    unsigned short* Kb = (unsigned short*)(ws + 35655680);       // [64][1024][128]
    unsigned short* Vb = (unsigned short*)(ws + 52432896);       // [64][128][1024] (m-permuted)
    unsigned short* ot = ht;                                     // reuse h_t region

    k_wconv<<<dim3(4096), dim3(256), 0, stream>>>(qkvw, projw, wq);
    k_gn<<<dim3(512), dim3(256), 0, stream>>>(x, gnw, gnb, ht);
    k_gemm<<<dim3(1536), dim3(256), 0, stream>>>(wq, ht, qkvb, 0, Qb, Kb, Vb, nullptr, nullptr);
    k_attn<<<dim3(8, 64), dim3(256), 0, stream>>>(Qb, Kb, Vb, ot);
    k_gemm<<<dim3(512), dim3(256), 0, stream>>>(wp, ot, projb, 1, nullptr, nullptr, nullptr, x, out);
}

// Round 6
// 127.660 us; speedup vs baseline: 1.7828x; 1.0068x over previous
//
#include <hip/hip_runtime.h>

typedef __attribute__((ext_vector_type(4))) float f32x4;
typedef __attribute__((ext_vector_type(8))) short s16x8;

#define MFMA16(a, b, c) __builtin_amdgcn_mfma_f32_16x16x32_bf16((a), (b), (c), 0, 0, 0)

__device__ __forceinline__ unsigned short f2bf(float f) {
    union { float f; unsigned u; } v; v.f = f;
    unsigned u = v.u + 0x7FFFu + ((v.u >> 16) & 1u);
    return (unsigned short)(u >> 16);
}

__device__ __forceinline__ unsigned cvtpk(float lo, float hi) {
    unsigned r;
    asm("v_cvt_pk_bf16_f32 %0, %1, %2" : "=v"(r) : "v"(lo), "v"(hi));
    return r;
}

__device__ __forceinline__ float exp2f_fast(float x) {
    float r;
    asm("v_exp_f32 %0, %1" : "=v"(r) : "v"(x));
    return r;
}

__device__ __forceinline__ void gll16(const unsigned short* g, unsigned short* l) {
    __builtin_amdgcn_global_load_lds((const __attribute__((address_space(1))) void*)g,
                                     (__attribute__((address_space(3))) void*)l, 16, 0, 0);
}

// ---------------- kernel 1: convert qkv_w / proj_w fp32 -> bf16 ----------------
__global__ __launch_bounds__(256) void k_wconv(const float* __restrict__ qkv_w,
                                               const float* __restrict__ proj_w,
                                               unsigned short* __restrict__ wout) {
    int i = blockIdx.x * 256 + threadIdx.x;
    const int NQ = 3 * 512 * 512;
    float v = (i < NQ) ? qkv_w[i] : proj_w[i - NQ];
    wout[i] = f2bf(v);
}

// ------- kernel 2: fused group-norm (stats + apply + transpose) per (b,g) -------
__global__ __launch_bounds__(256) void k_gn(const float* __restrict__ x,
                                            const float* __restrict__ gnw,
                                            const float* __restrict__ gnb,
                                            unsigned short* __restrict__ h_t) {
    int bg = blockIdx.x;
    int b = bg >> 5, g = bg & 31;
    int t = threadIdx.x;
    const float4* p = (const float4*)(x + (size_t)bg * 16384);
    float s = 0.f, ss = 0.f;
    for (int i = t; i < 4096; i += 256) {
        float4 v = p[i];
        s += v.x + v.y + v.z + v.w;
        ss += v.x * v.x + v.y * v.y + v.z * v.z + v.w * v.w;
    }
    for (int w = 1; w < 64; w <<= 1) { s += __shfl_xor(s, w); ss += __shfl_xor(ss, w); }
    __shared__ float rs[4], rss[4], mv[2];
    __shared__ unsigned short ldt[1024][18];  // padded: stride 36B kills conflicts
    int wid = t >> 6;
    if ((t & 63) == 0) { rs[wid] = s; rss[wid] = ss; }
    __syncthreads();
    if (t == 0) {
        float S = rs[0] + rs[1] + rs[2] + rs[3];
        float SS = rss[0] + rss[1] + rss[2] + rss[3];
        float mean = S * (1.f / 16384.f);
        float var = SS * (1.f / 16384.f) - mean * mean;
        mv[0] = mean; mv[1] = rsqrtf(var + 1e-5f);
    }
    __syncthreads();
    int c = t >> 4, f4 = t & 15;
    float mean = mv[0], rstd = mv[1];
    float sc = gnw[g * 16 + c] * rstd;
    float sh = gnb[g * 16 + c] - mean * sc;
    const float4* pc = (const float4*)(x + ((size_t)(b * 512 + g * 16 + c)) * 1024);
#pragma unroll
    for (int i = 0; i < 16; ++i) {
        int n = i * 64 + f4 * 4;
        float4 v = pc[n >> 2];
        ldt[n + 0][c] = f2bf(v.x * sc + sh);
        ldt[n + 1][c] = f2bf(v.y * sc + sh);
        ldt[n + 2][c] = f2bf(v.z * sc + sh);
        ldt[n + 3][c] = f2bf(v.w * sc + sh);
    }
    __syncthreads();
    int half = t & 1;
#pragma unroll
    for (int i = 0; i < 8; ++i) {
        int row = i * 128 + (t >> 1);
        *(uint4*)(h_t + ((size_t)(b * 1024 + row)) * 512 + g * 16 + half * 8) =
            *(const uint4*)(&ldt[row][half * 8]);
    }
}

// ---------------- kernel 4/6: BT-GEMM, 128x128 tile, K=512 ----------------
__global__ __launch_bounds__(256) void k_gemm(const unsigned short* __restrict__ A,
                                              const unsigned short* __restrict__ Bt,
                                              const float* __restrict__ bias, int mode,
                                              unsigned short* __restrict__ Qo,
                                              unsigned short* __restrict__ Ko,
                                              unsigned short* __restrict__ Vo,
                                              const float* __restrict__ xres,
                                              float* __restrict__ out) {
    const int Kd = 512;
    int id = blockIdx.x;
    int xcd = id & 7, j = id >> 3;
    int nt = xcd + 8 * (j & 15);   // B-tile: 16 per XCD, L2-resident (2.1 MB)
    int mt = j >> 4;               // A sweeps within XCD
    int t = threadIdx.x, wid = t >> 6, lane = t & 63;
    int lm = lane & 15, q4 = lane >> 4;
    int wm = wid >> 1, wn = wid & 1;
    __shared__ unsigned short ldsA[2][4096];
    __shared__ unsigned short ldsB[2][4096];
    int m0 = mt * 128, n0 = nt * 128;

    const unsigned short* gA[2];
    const unsigned short* gB[2];
    unsigned short* dA[2][2];
    unsigned short* dB[2][2];
#pragma unroll
    for (int h = 0; h < 2; ++h) {
        int cib = h * 256 + wid * 64;
        int ci = cib + lane;
        int r = ci >> 2;
        int cc = (ci & 3) ^ (r & 3);
        gA[h] = A + (size_t)(m0 + r) * Kd + cc * 8;
        gB[h] = Bt + (size_t)(n0 + r) * Kd + cc * 8;
        dA[0][h] = &ldsA[0][cib * 8];
        dA[1][h] = &ldsA[1][cib * 8];
        dB[0][h] = &ldsB[0][cib * 8];
        dB[1][h] = &ldsB[1][cib * 8];
    }

    f32x4 z = {0.f, 0.f, 0.f, 0.f};
    f32x4 acc[4][4];
#pragma unroll
    for (int fi = 0; fi < 4; ++fi)
#pragma unroll
        for (int fj = 0; fj < 4; ++fj) acc[fi][fj] = z;

    gll16(gA[0], dA[0][0]); gll16(gB[0], dB[0][0]);
    gll16(gA[1], dA[0][1]); gll16(gB[1], dB[0][1]);
    gA[0] += 32; gA[1] += 32; gB[0] += 32; gB[1] += 32;

    const int NK = 16;
    for (int ks = 0; ks < NK; ++ks) {
        int cur = ks & 1;
        if (ks + 1 < NK) {
            int nb = cur ^ 1;
            gll16(gA[0], dA[nb][0]); gll16(gB[0], dB[nb][0]);
            gll16(gA[1], dA[nb][1]); gll16(gB[1], dB[nb][1]);
            gA[0] += 32; gA[1] += 32; gB[0] += 32; gB[1] += 32;
            asm volatile("s_waitcnt vmcnt(4)" ::: "memory");
        } else {
            asm volatile("s_waitcnt vmcnt(0)" ::: "memory");
        }
        __builtin_amdgcn_s_barrier();
        asm volatile("" ::: "memory");
        const unsigned short* lA = ldsA[cur];
        const unsigned short* lB = ldsB[cur];
        s16x8 af[4], bg[4];
#pragma unroll
        for (int fi = 0; fi < 4; ++fi) {
            int rA = wm * 64 + fi * 16 + lm;
            af[fi] = *(const s16x8*)&lA[(rA * 4 + (q4 ^ (lm & 3))) * 8];
        }
#pragma unroll
        for (int fj = 0; fj < 4; ++fj) {
            int rB = wn * 64 + fj * 16 + lm;
            bg[fj] = *(const s16x8*)&lB[(rB * 4 + (q4 ^ (lm & 3))) * 8];
        }
#pragma unroll
        for (int fi = 0; fi < 4; ++fi)
#pragma unroll
            for (int fj = 0; fj < 4; ++fj) acc[fi][fj] = MFMA16(af[fi], bg[fj], acc[fi][fj]);
        asm volatile("" ::: "memory");
        __builtin_amdgcn_s_barrier();
    }

    if (mode == 0) {
        int part = mt >> 2;  // 0=Q 1=K 2=V (M-tile never straddles parts)
        int head = mt & 3;
        int b = nt >> 3;
        int bh = b * 4 + head;
        const float qscale = 0.08838834764831845f * 1.4426950408889634f;  // 1/sqrt(128)*log2e
#pragma unroll
        for (int fi = 0; fi < 4; ++fi) {
            int ddb = wm * 64 + fi * 16 + 4 * q4;  // + i -> d within head
            float bv[4];
#pragma unroll
            for (int i = 0; i < 4; ++i) bv[i] = bias[mt * 128 + ddb + i];
#pragma unroll
            for (int fj = 0; fj < 4; ++fj) {
                int n = ((nt & 7) << 7) + wn * 64 + fj * 16 + lm;
                f32x4 v = acc[fi][fj];
                if (part == 0) {
                    uint2 pr;
                    pr.x = cvtpk((v[0] + bv[0]) * qscale, (v[1] + bv[1]) * qscale);
                    pr.y = cvtpk((v[2] + bv[2]) * qscale, (v[3] + bv[3]) * qscale);
                    *(uint2*)(Qo + ((size_t)bh * 1024 + n) * 128 + ddb) = pr;
                } else if (part == 1) {
                    uint2 pr;
                    pr.x = cvtpk(v[0] + bv[0], v[1] + bv[1]);
                    pr.y = cvtpk(v[2] + bv[2], v[3] + bv[3]);
                    *(uint2*)(Ko + ((size_t)bh * 1024 + n) * 128 + ddb) = pr;
                } else {
                    // permute m within each 32-block so attn's PV A-frag k-order
                    // matches the lane-local P register order (perm(8a+j))
                    int r = (fj & 1) * 16 + lm;
                    int kidx = (lm >> 2) * 8 + (fj & 1) * 4 + (lm & 3);
                    int np = n - r + kidx;
#pragma unroll
                    for (int i = 0; i < 4; ++i)
                        Vo[((size_t)bh * 128 + ddb + i) * 1024 + np] = f2bf(v[i] + bv[i]);
                }
            }
        }
    } else {
        int b = nt >> 3;
#pragma unroll
        for (int fi = 0; fi < 4; ++fi) {
            int ocb = m0 + wm * 64 + fi * 16 + 4 * q4;
            float bv[4];
#pragma unroll
            for (int i = 0; i < 4; ++i) bv[i] = bias[ocb + i];
#pragma unroll
            for (int fj = 0; fj < 4; ++fj) {
                int n = ((nt & 7) << 7) + wn * 64 + fj * 16 + lm;
#pragma unroll
                for (int i = 0; i < 4; ++i) {
                    size_t idx = ((size_t)b * 512 + ocb + i) * 1024 + n;
                    out[idx] = xres[idx] + bv[i] + acc[fi][fj][i];
                }
            }
        }
    }
}

// ------- kernel 5: flash attention, 32 q/wave, KVBLK=64, intra-tile skew -------
// Per tile: QK(h0); QK(h1) issued back-to-back; softmax(h0) VALU retires under
// QK(h1); PV(h0); softmax(h1) retires under PV(h0); PV(h1). MFMA/VALU overlap
// within one wave (2 waves/SIMD is grid-capped, so VGPR growth is free).
__global__ __launch_bounds__(256, 2) void k_attn(const unsigned short* __restrict__ Q,
                                                 const unsigned short* __restrict__ K,
                                                 const unsigned short* __restrict__ V,
                                                 unsigned short* __restrict__ o_t) {
    int id = blockIdx.y * 8 + blockIdx.x;
    int bh = (id & 7) + ((id >> 6) << 3);   // XCD swizzle: all 8 q-blocks of a bh
    int qb = (id >> 3) & 7;                 // land on one XCD for K/V L2 reuse
    int t = threadIdx.x, wid = t >> 6, lane = t & 63;
    int lm = lane & 15, q4 = lane >> 4;
    __shared__ unsigned short ldsK[2][8192];  // [m=64][d=128], chunk^(m&7) swizzle
    __shared__ unsigned short ldsV[2][8192];  // [d=128][k=64], chunk^(d&7) swizzle
    const unsigned short* Qg = Q + ((size_t)bh * 1024 + qb * 128 + wid * 32) * 128;
    const unsigned short* Kg = K + (size_t)bh * 1024 * 128;
    const unsigned short* Vg = V + (size_t)bh * 128 * 1024;

    s16x8 qf0[4], qf1[4];
#pragma unroll
    for (int dc = 0; dc < 4; ++dc) {
        qf0[dc] = *(const s16x8*)&Qg[lm * 128 + dc * 32 + q4 * 8];
        qf1[dc] = *(const s16x8*)&Qg[(16 + lm) * 128 + dc * 32 + q4 * 8];
    }

    const unsigned short* gk[4];
    const unsigned short* gv[4];
    unsigned short* lkd[2][4];
    unsigned short* lvd[2][4];
#pragma unroll
    for (int h = 0; h < 4; ++h) {
        int cib = h * 256 + wid * 64;
        int ci = cib + lane;
        int mr = ci >> 4, cl = ci & 15;
        gk[h] = Kg + mr * 128 + (cl ^ (mr & 7)) * 8;
        int d = ci >> 3, kc = ci & 7;
        gv[h] = Vg + (size_t)d * 1024 + (kc ^ (d & 7)) * 8;
        lkd[0][h] = &ldsK[0][cib * 8];
        lkd[1][h] = &ldsK[1][cib * 8];
        lvd[0][h] = &ldsV[0][cib * 8];
        lvd[1][h] = &ldsV[1][cib * 8];
    }
#pragma unroll
    for (int h = 0; h < 4; ++h) { gll16(gk[h], lkd[0][h]); gll16(gv[h], lvd[0][h]); }
#pragma unroll
    for (int h = 0; h < 4; ++h) { gk[h] += 8192; gv[h] += 64; }

    f32x4 z = {0.f, 0.f, 0.f, 0.f};
    f32x4 oa[8], ob[8];
#pragma unroll
    for (int i = 0; i < 8; ++i) { oa[i] = z; ob[i] = z; }
    float mra = -1e30f, mrb = -1e30f, lpa = 0.f, lpb = 0.f;

    // softmax for one 32-key half: S-regs in, P-frags out; updates m/l/oacc
    auto smax = [&](const f32x4& s0a, const f32x4& s0b, const f32x4& s1a,
                    const f32x4& s1b, s16x8& fav, s16x8& fbv) {
        float tma = fmaxf(fmaxf(fmaxf(s0a[0], s0a[1]), fmaxf(s0a[2], s0a[3])),
                          fmaxf(fmaxf(s1a[0], s1a[1]), fmaxf(s1a[2], s1a[3])));
        float tmb = fmaxf(fmaxf(fmaxf(s0b[0], s0b[1]), fmaxf(s0b[2], s0b[3])),
                          fmaxf(fmaxf(s1b[0], s1b[1]), fmaxf(s1b[2], s1b[3])));
        if (!__all(tma <= mra + 8.f && tmb <= mrb + 8.f)) {  // defer-max (T13)
            tma = fmaxf(tma, __shfl_xor(tma, 16));
            tma = fmaxf(tma, __shfl_xor(tma, 32));
            tmb = fmaxf(tmb, __shfl_xor(tmb, 16));
            tmb = fmaxf(tmb, __shfl_xor(tmb, 32));
            float mna = fmaxf(mra, tma), mnb = fmaxf(mrb, tmb);
            float ca = exp2f_fast(mra - mna), cb = exp2f_fast(mrb - mnb);
            lpa *= ca; lpb *= cb;
#pragma unroll
            for (int t8 = 0; t8 < 8; ++t8)
#pragma unroll
                for (int i = 0; i < 4; ++i) { oa[t8][i] *= ca; ob[t8][i] *= cb; }
            mra = mna; mrb = mnb;
        }
        float pa[8], pb[8];
#pragma unroll
        for (int i = 0; i < 4; ++i) {
            pa[i]     = exp2f_fast(s0a[i] - mra);
            pa[4 + i] = exp2f_fast(s1a[i] - mra);
            pb[i]     = exp2f_fast(s0b[i] - mrb);
            pb[4 + i] = exp2f_fast(s1b[i] - mrb);
        }
#pragma unroll
        for (int i = 0; i < 8; ++i) { lpa += pa[i]; lpb += pb[i]; }
        union { s16x8 v; unsigned u[4]; } fa, fb;
        fa.u[0] = cvtpk(pa[0], pa[1]); fa.u[1] = cvtpk(pa[2], pa[3]);
        fa.u[2] = cvtpk(pa[4], pa[5]); fa.u[3] = cvtpk(pa[6], pa[7]);
        fb.u[0] = cvtpk(pb[0], pb[1]); fb.u[1] = cvtpk(pb[2], pb[3]);
        fb.u[2] = cvtpk(pb[4], pb[5]); fb.u[3] = cvtpk(pb[6], pb[7]);
        fav = fa.v; fbv = fb.v;
    };

    for (int ms = 0; ms < 16; ++ms) {
        int cur = ms & 1;
        if (ms < 15) {
            int nb = cur ^ 1;
#pragma unroll
            for (int h = 0; h < 4; ++h) { gll16(gk[h], lkd[nb][h]); gll16(gv[h], lvd[nb][h]); }
#pragma unroll
            for (int h = 0; h < 4; ++h) { gk[h] += 8192; gv[h] += 64; }
            asm volatile("s_waitcnt vmcnt(8)" ::: "memory");
        } else {
            asm volatile("s_waitcnt vmcnt(0)" ::: "memory");
        }
        __builtin_amdgcn_s_barrier();
        const unsigned short* lK = ldsK[cur];
        const unsigned short* lV = ldsV[cur];

        // ---- QK h0 then QK h1, issued back-to-back ----
        f32x4 sa0 = z, sb0 = z, sc0 = z, sd0 = z;
        f32x4 sa1 = z, sb1 = z, sc1 = z, sd1 = z;
        __builtin_amdgcn_s_setprio(1);
#pragma unroll
        for (int dc = 0; dc < 4; ++dc) {
            int sw = ((dc * 4 + q4) ^ (lm & 7)) * 8;
            s16x8 k0 = *(const s16x8*)&lK[lm * 128 + sw];
            s16x8 k1 = *(const s16x8*)&lK[(16 + lm) * 128 + sw];
            sa0 = MFMA16(k0, qf0[dc], sa0);
            sb0 = MFMA16(k0, qf1[dc], sb0);
            sc0 = MFMA16(k1, qf0[dc], sc0);
            sd0 = MFMA16(k1, qf1[dc], sd0);
        }
#pragma unroll
        for (int dc = 0; dc < 4; ++dc) {
            int sw = ((dc * 4 + q4) ^ (lm & 7)) * 8;
            s16x8 k0 = *(const s16x8*)&lK[(32 + lm) * 128 + sw];
            s16x8 k1 = *(const s16x8*)&lK[(48 + lm) * 128 + sw];
            sa1 = MFMA16(k0, qf0[dc], sa1);
            sb1 = MFMA16(k0, qf1[dc], sb1);
            sc1 = MFMA16(k1, qf0[dc], sc1);
            sd1 = MFMA16(k1, qf1[dc], sd1);
        }
        __builtin_amdgcn_s_setprio(0);

        // ---- softmax h0 (VALU; retires under QK h1 on the matrix pipe) ----
        s16x8 fa0, fb0;
        smax(sa0, sb0, sc0, sd0, fa0, fb0);

        // ---- PV h0 ----
        __builtin_amdgcn_s_setprio(1);
#pragma unroll
        for (int t8 = 0; t8 < 8; ++t8) {
            int r = t8 * 16 + lm;
            s16x8 vf = *(const s16x8*)&lV[r * 64 + ((q4 ^ (lm & 7)) * 8)];
            oa[t8] = MFMA16(vf, fa0, oa[t8]);
            ob[t8] = MFMA16(vf, fb0, ob[t8]);
        }
        __builtin_amdgcn_s_setprio(0);

        // ---- softmax h1 (VALU; retires under PV h0) ----
        s16x8 fa1, fb1;
        smax(sa1, sb1, sc1, sd1, fa1, fb1);

        // ---- PV h1 ----
        __builtin_amdgcn_s_setprio(1);
#pragma unroll
        for (int t8 = 0; t8 < 8; ++t8) {
            int r = t8 * 16 + lm;
            s16x8 vf = *(const s16x8*)&lV[r * 64 + (((4 + q4) ^ (lm & 7)) * 8)];
            oa[t8] = MFMA16(vf, fa1, oa[t8]);
            ob[t8] = MFMA16(vf, fb1, ob[t8]);
        }
        __builtin_amdgcn_s_setprio(0);
        __builtin_amdgcn_s_barrier();
    }

    lpa += __shfl_xor(lpa, 16); lpa += __shfl_xor(lpa, 32);
    lpb += __shfl_xor(lpb, 16); lpb += __shfl_xor(lpb, 32);
    float inva = 1.f / lpa, invb = 1.f / lpb;
    int b = bh >> 2, head = bh & 3;
    size_t rowa = (size_t)b * 1024 + qb * 128 + wid * 32 + lm;
    unsigned short* da = o_t + rowa * 512 + head * 128;
    unsigned short* db = da + (size_t)16 * 512;
#pragma unroll
    for (int t8 = 0; t8 < 8; ++t8) {
        uint2 pr;
        pr.x = cvtpk(oa[t8][0] * inva, oa[t8][1] * inva);
        pr.y = cvtpk(oa[t8][2] * inva, oa[t8][3] * inva);
        *(uint2*)&da[t8 * 16 + q4 * 4] = pr;
        pr.x = cvtpk(ob[t8][0] * invb, ob[t8][1] * invb);
        pr.y = cvtpk(ob[t8][2] * invb, ob[t8][3] * invb);
        *(uint2*)&db[t8 * 16 + q4 * 4] = pr;
    }
}

extern "C" void kernel_launch(void* const* d_in, const int* in_sizes, int n_in,
                              void* d_out, int out_size, void* d_ws, size_t ws_size,
                              hipStream_t stream) {
    const float* x = (const float*)d_in[0];
    const float* gnw = (const float*)d_in[1];
    const float* gnb = (const float*)d_in[2];
    const float* qkvw = (const float*)d_in[3];
    const float* qkvb = (const float*)d_in[4];
    const float* projw = (const float*)d_in[5];
    const float* projb = (const float*)d_in[6];
    float* out = (float*)d_out;
    char* ws = (char*)d_ws;

    unsigned short* wq = (unsigned short*)(ws);                  // 1536x512 bf16
    unsigned short* wp = (unsigned short*)(ws + 1572864);        // 512x512 bf16
    unsigned short* ht = (unsigned short*)(ws + 2101248);        // h_t [16384][512] bf16
    unsigned short* Qb = (unsigned short*)(ws + 18878464);       // [64][1024][128] (pre-scaled)
    unsigned short* Kb = (unsigned short*)(ws + 35655680);       // [64][1024][128]
    unsigned short* Vb = (unsigned short*)(ws + 52432896);       // [64][128][1024] (m-permuted)
    unsigned short* ot = ht;                                     // reuse h_t region

    k_wconv<<<dim3(4096), dim3(256), 0, stream>>>(qkvw, projw, wq);
    k_gn<<<dim3(512), dim3(256), 0, stream>>>(x, gnw, gnb, ht);
    k_gemm<<<dim3(1536), dim3(256), 0, stream>>>(wq, ht, qkvb, 0, Qb, Kb, Vb, nullptr, nullptr);
    k_attn<<<dim3(8, 64), dim3(256), 0, stream>>>(Qb, Kb, Vb, ot);
    k_gemm<<<dim3(512), dim3(256), 0, stream>>>(wp, ot, projb, 1, nullptr, nullptr, nullptr, x, out);
}